// Round 1
// baseline (1100.333 us; speedup 1.0000x reference)
//
#include <hip/hip_runtime.h>
#include <math.h>

// Problem constants
#define Bb   8
#define Tseq 2048
#define Cch  512
#define Hh   4
#define Kk   128
#define Mrows (Bb * Tseq)   // 16384

// GEMM tile
#define BM 64
#define BN 64
#define BK 16

// ---------------------------------------------------------------------------
// QKV projection GEMM: out[m, n] = sum_c X[m,c] * Wq[h= n>>7, c, k = n&127] + bias[n]
// X: [16384, 512], W: (H,C,K) = (4,512,128) flat, bias: [512] (=(H,K) flat)
// ---------------------------------------------------------------------------
__global__ __launch_bounds__(256) void gemm_qkv_kernel(
    const float* __restrict__ X, const float* __restrict__ W,
    const float* __restrict__ bias, float* __restrict__ out) {
  __shared__ float As[BK][BM];
  __shared__ float Bs[BK][BN];
  const int tid = threadIdx.x;
  const int tx = tid & 15, ty = tid >> 4;
  const int n0 = blockIdx.x * BN;
  const int m0 = blockIdx.y * BM;
  const int head = n0 >> 7;           // BN=64 tiles never straddle a head (K=128)
  const int kb = n0 & 127;
  const int arow = tid >> 2, acol = (tid & 3) * 4;
  float acc[4][4] = {};
  for (int k0 = 0; k0 < Cch; k0 += BK) {
    float4 av = *(const float4*)(X + (size_t)(m0 + arow) * Cch + k0 + acol);
    As[acol + 0][arow] = av.x;
    As[acol + 1][arow] = av.y;
    As[acol + 2][arow] = av.z;
    As[acol + 3][arow] = av.w;
    float4 bv = *(const float4*)(W + (size_t)head * (Cch * Kk)
                                 + (size_t)(k0 + ty) * Kk + kb + tx * 4);
    *(float4*)(&Bs[ty][tx * 4]) = bv;
    __syncthreads();
#pragma unroll
    for (int kk = 0; kk < BK; ++kk) {
      float4 a = *(const float4*)(&As[kk][ty * 4]);
      float4 b = *(const float4*)(&Bs[kk][tx * 4]);
      float ar[4] = {a.x, a.y, a.z, a.w};
      float br[4] = {b.x, b.y, b.z, b.w};
#pragma unroll
      for (int i = 0; i < 4; ++i)
#pragma unroll
        for (int j = 0; j < 4; ++j) acc[i][j] = fmaf(ar[i], br[j], acc[i][j]);
    }
    __syncthreads();
  }
#pragma unroll
  for (int i = 0; i < 4; ++i) {
    const int m = m0 + ty * 4 + i;
    const int n = n0 + tx * 4;
    float4 o;
    o.x = acc[i][0] + bias[n + 0];
    o.y = acc[i][1] + bias[n + 1];
    o.z = acc[i][2] + bias[n + 2];
    o.w = acc[i][3] + bias[n + 3];
    *(float4*)(out + (size_t)m * Cch + n) = o;
  }
}

// ---------------------------------------------------------------------------
// Head-combine GEMM: out[m,c] = sum_j cat[m,j] * Wo[j,c] + bo[c]
// ---------------------------------------------------------------------------
__global__ __launch_bounds__(256) void gemm_combine_kernel(
    const float* __restrict__ X, const float* __restrict__ W,
    const float* __restrict__ bias, float* __restrict__ out) {
  __shared__ float As[BK][BM];
  __shared__ float Bs[BK][BN];
  const int tid = threadIdx.x;
  const int tx = tid & 15, ty = tid >> 4;
  const int n0 = blockIdx.x * BN;
  const int m0 = blockIdx.y * BM;
  const int arow = tid >> 2, acol = (tid & 3) * 4;
  float acc[4][4] = {};
  for (int k0 = 0; k0 < Cch; k0 += BK) {
    float4 av = *(const float4*)(X + (size_t)(m0 + arow) * Cch + k0 + acol);
    As[acol + 0][arow] = av.x;
    As[acol + 1][arow] = av.y;
    As[acol + 2][arow] = av.z;
    As[acol + 3][arow] = av.w;
    float4 bv = *(const float4*)(W + (size_t)(k0 + ty) * Cch + n0 + tx * 4);
    *(float4*)(&Bs[ty][tx * 4]) = bv;
    __syncthreads();
#pragma unroll
    for (int kk = 0; kk < BK; ++kk) {
      float4 a = *(const float4*)(&As[kk][ty * 4]);
      float4 b = *(const float4*)(&Bs[kk][tx * 4]);
      float ar[4] = {a.x, a.y, a.z, a.w};
      float br[4] = {b.x, b.y, b.z, b.w};
#pragma unroll
      for (int i = 0; i < 4; ++i)
#pragma unroll
        for (int j = 0; j < 4; ++j) acc[i][j] = fmaf(ar[i], br[j], acc[i][j]);
    }
    __syncthreads();
  }
#pragma unroll
  for (int i = 0; i < 4; ++i) {
    const int m = m0 + ty * 4 + i;
    const int n = n0 + tx * 4;
    float4 o;
    o.x = acc[i][0] + bias[n + 0];
    o.y = acc[i][1] + bias[n + 1];
    o.z = acc[i][2] + bias[n + 2];
    o.w = acc[i][3] + bias[n + 3];
    *(float4*)(out + (size_t)m * Cch + n) = o;
  }
}

// ---------------------------------------------------------------------------
// Dilated causal conv as GEMM over K0 = 4*512 with row-gathered A, fused
// bias + relu + residual + leaky_relu epilogue.
// conv[m, co] = sum_{j=0..3} sum_ci out2[m + 4j - 12, ci] * Wc[j, ci, co]
// (rows before start of the batch element are zero; blocks never straddle
//  a batch boundary since T=2048 is a multiple of BM=64)
// ---------------------------------------------------------------------------
__global__ __launch_bounds__(256) void conv_fused_kernel(
    const float* __restrict__ A, const float* __restrict__ Wc,
    const float* __restrict__ bc, const float* __restrict__ x,
    float* __restrict__ out) {
  __shared__ float As[BK][BM];
  __shared__ float Bs[BK][BN];
  const int tid = threadIdx.x;
  const int tx = tid & 15, ty = tid >> 4;
  const int n0 = blockIdx.x * BN;
  const int m0 = blockIdx.y * BM;
  const int arow = tid >> 2, acol = (tid & 3) * 4;
  const int tloc = (m0 + arow) & (Tseq - 1);
  float acc[4][4] = {};
  for (int k0 = 0; k0 < 4 * Cch; k0 += BK) {
    const int j = k0 >> 9;            // conv tap; constant within a K-tile
    const int cin0 = k0 & 511;
    const int shift = 4 * j - 12;
    float4 av;
    if (tloc + shift >= 0) {
      av = *(const float4*)(A + (size_t)(m0 + arow + shift) * Cch + cin0 + acol);
    } else {
      av = make_float4(0.f, 0.f, 0.f, 0.f);
    }
    As[acol + 0][arow] = av.x;
    As[acol + 1][arow] = av.y;
    As[acol + 2][arow] = av.z;
    As[acol + 3][arow] = av.w;
    float4 bv = *(const float4*)(Wc + (size_t)(k0 + ty) * Cch + n0 + tx * 4);
    *(float4*)(&Bs[ty][tx * 4]) = bv;
    __syncthreads();
#pragma unroll
    for (int kk = 0; kk < BK; ++kk) {
      float4 a = *(const float4*)(&As[kk][ty * 4]);
      float4 b = *(const float4*)(&Bs[kk][tx * 4]);
      float ar[4] = {a.x, a.y, a.z, a.w};
      float br[4] = {b.x, b.y, b.z, b.w};
#pragma unroll
      for (int i = 0; i < 4; ++i)
#pragma unroll
        for (int jj = 0; jj < 4; ++jj) acc[i][jj] = fmaf(ar[i], br[jj], acc[i][jj]);
    }
    __syncthreads();
  }
#pragma unroll
  for (int i = 0; i < 4; ++i) {
    const int m = m0 + ty * 4 + i;
    const int n = n0 + tx * 4;
    float4 xo = *(const float4*)(x + (size_t)m * Cch + n);
    float r[4];
#pragma unroll
    for (int jj = 0; jj < 4; ++jj) {
      float v = acc[i][jj] + bc[n + jj];
      v = fmaxf(v, 0.f);                       // relu(conv + bc)
      v += ((const float*)&xo)[jj];            // + residual x
      r[jj] = (v >= 0.f) ? v : 0.2f * v;       // leaky_relu(0.2)
    }
    float4 o = make_float4(r[0], r[1], r[2], r[3]);
    *(float4*)(out + (size_t)m * Cch + n) = o;
  }
}

// ---------------------------------------------------------------------------
// Banded attention: softmax over |t-s|<=3 (clipped at sequence edges), then
// weighted sum of v. One wave per (b,h,t); lane handles dims 2*lane, 2*lane+1.
// q,k,v,cat all laid out [B*T, H*128] with column h*128+d.
// ---------------------------------------------------------------------------
__global__ __launch_bounds__(64) void attn_band_kernel(
    const float* __restrict__ q, const float* __restrict__ k,
    const float* __restrict__ v, float* __restrict__ cat) {
  const int t = blockIdx.x;
  const int bh = blockIdx.y;
  const int b = bh >> 2, h = bh & 3;
  const int lane = threadIdx.x;
  const int d0 = lane * 2;
  const size_t rowbase = ((size_t)(b * Tseq + t)) * Cch + h * Kk;
  const float q0 = q[rowbase + d0];
  const float q1 = q[rowbase + d0 + 1];
  const float scale = 0.08838834764831845f;  // 1/sqrt(128)
  float score[7];
#pragma unroll
  for (int i = 0; i < 7; ++i) {
    const int s = t - 3 + i;
    const bool valid = (s >= 0) && (s < Tseq);
    float p = 0.f;
    if (valid) {
      const size_t sb = ((size_t)(b * Tseq + s)) * Cch + h * Kk;
      p = q0 * k[sb + d0] + q1 * k[sb + d0 + 1];
    }
#pragma unroll
    for (int off = 1; off < 64; off <<= 1) p += __shfl_xor(p, off);
    score[i] = valid ? p * scale : -1e30f;
  }
  float mx = score[0];
#pragma unroll
  for (int i = 1; i < 7; ++i) mx = fmaxf(mx, score[i]);
  float w[7];
  float denom = 0.f;
#pragma unroll
  for (int i = 0; i < 7; ++i) {
    w[i] = (score[i] > -1e29f) ? expf(score[i] - mx) : 0.f;
    denom += w[i];
  }
  const float inv = 1.f / denom;
  float o0 = 0.f, o1 = 0.f;
#pragma unroll
  for (int i = 0; i < 7; ++i) {
    if (w[i] != 0.f) {
      const int s = t - 3 + i;
      const size_t sb = ((size_t)(b * Tseq + s)) * Cch + h * Kk;
      o0 += w[i] * v[sb + d0];
      o1 += w[i] * v[sb + d0 + 1];
    }
  }
  cat[rowbase + d0] = o0 * inv;
  cat[rowbase + d0 + 1] = o1 * inv;
}

// ---------------------------------------------------------------------------
extern "C" void kernel_launch(void* const* d_in, const int* in_sizes, int n_in,
                              void* d_out, int out_size, void* d_ws, size_t ws_size,
                              hipStream_t stream) {
  const float* x  = (const float*)d_in[0];
  const float* Wq = (const float*)d_in[1];
  const float* bq = (const float*)d_in[2];
  const float* Wk = (const float*)d_in[3];
  const float* bk = (const float*)d_in[4];
  const float* Wv = (const float*)d_in[5];
  const float* bv = (const float*)d_in[6];
  const float* Wo = (const float*)d_in[7];
  const float* bo = (const float*)d_in[8];
  const float* Wc = (const float*)d_in[9];
  const float* bc = (const float*)d_in[10];
  float* out = (float*)d_out;

  // Workspace layout (each buffer 16384*512 floats = 32 MiB):
  //   q | k | v | cat   (out2 aliases k — k is dead once attention completes)
  const size_t BUF = (size_t)Mrows * Cch;  // 8,388,608 floats
  float* q    = (float*)d_ws;
  float* kbuf = q + BUF;
  float* vbuf = kbuf + BUF;
  float* cat  = vbuf + BUF;
  float* out2 = kbuf;  // alias

  dim3 gemm_grid(Cch / BN, Mrows / BM);  // (8, 256)
  gemm_qkv_kernel<<<gemm_grid, 256, 0, stream>>>(x, Wq, bq, q);
  gemm_qkv_kernel<<<gemm_grid, 256, 0, stream>>>(x, Wk, bk, kbuf);
  gemm_qkv_kernel<<<gemm_grid, 256, 0, stream>>>(x, Wv, bv, vbuf);

  attn_band_kernel<<<dim3(Tseq, Bb * Hh), 64, 0, stream>>>(q, kbuf, vbuf, cat);

  gemm_combine_kernel<<<gemm_grid, 256, 0, stream>>>(cat, Wo, bo, out2);

  conv_fused_kernel<<<gemm_grid, 256, 0, stream>>>(out2, Wc, bc, x, out);
}

// Round 2
// 302.640 us; speedup vs baseline: 3.6358x; 3.6358x over previous
//
#include <hip/hip_runtime.h>
#include <math.h>

#define Bb    8
#define Tseq  2048
#define Cch   512
#define Mrows 16384
#define Nqkv  1536

typedef __bf16 bf16x8 __attribute__((ext_vector_type(8)));
typedef __bf16 bf16x4 __attribute__((ext_vector_type(4)));
typedef __bf16 bf16x2 __attribute__((ext_vector_type(2)));
typedef float  f32x4  __attribute__((ext_vector_type(4)));

// async global->LDS, 16B per lane. LDS dest must be the WAVE-UNIFORM chunk
// base; HW scatters lane i to base + i*16.
__device__ __forceinline__ void gld_lds16(const void* g, void* l) {
  __builtin_amdgcn_global_load_lds(
      (const __attribute__((address_space(1))) unsigned int*)g,
      (__attribute__((address_space(3))) unsigned int*)l, 16, 0, 0);
}

// ---------------------------------------------------------------------------
// bf16 MFMA GEMM, B^T input ([N][K]), bias (fp32, selected by col>>9 section),
// bf16 output. Tile 128x128, BK=64, 4 waves (2x2), each wave 64x64 via 4x4
// MFMA 16x16x32 tiles.
// ---------------------------------------------------------------------------
__global__ __launch_bounds__(256, 2) void gemm_bt_bf16_kernel(
    const __bf16* __restrict__ A, int lda,
    const __bf16* __restrict__ Bt, int K,
    const float* __restrict__ b0, const float* __restrict__ b1,
    const float* __restrict__ b2,
    __bf16* __restrict__ out, int ldo) {
  __shared__ __align__(16) __bf16 As[128 * 64];
  __shared__ __align__(16) __bf16 Bs[128 * 64];
  const int tid = threadIdx.x;
  const int w = tid >> 6, lane = tid & 63;
  const int wm = w & 1, wn = w >> 1;
  const int lm = lane & 15, quad = lane >> 4;
  const int m0 = blockIdx.y * 128, n0 = blockIdx.x * 128;
  f32x4 acc[4][4] = {};
  for (int k0 = 0; k0 < K; k0 += 64) {
#pragma unroll
    for (int it = 0; it < 4; ++it) {
      const int c = w * 4 + it;          // chunk id 0..15
      const int e = c * 512 + lane * 8;  // element offset in tile
      const int row = e >> 6, col = e & 63;
      gld_lds16(A + (size_t)(m0 + row) * lda + k0 + col, &As[c * 512]);
      gld_lds16(Bt + (size_t)(n0 + row) * K + k0 + col, &Bs[c * 512]);
    }
    __syncthreads();
#pragma unroll
    for (int ks = 0; ks < 2; ++ks) {
      bf16x8 af[4], bfr[4];
#pragma unroll
      for (int i = 0; i < 4; ++i)
        af[i] = *(const bf16x8*)&As[(wm * 64 + i * 16 + lm) * 64 + ks * 32 + quad * 8];
#pragma unroll
      for (int j = 0; j < 4; ++j)
        bfr[j] = *(const bf16x8*)&Bs[(wn * 64 + j * 16 + lm) * 64 + ks * 32 + quad * 8];
#pragma unroll
      for (int i = 0; i < 4; ++i)
#pragma unroll
        for (int j = 0; j < 4; ++j)
          acc[i][j] = __builtin_amdgcn_mfma_f32_16x16x32_bf16(af[i], bfr[j], acc[i][j], 0, 0, 0);
    }
    __syncthreads();
  }
  // epilogue: D[row=quad*4+r][col=lane&15] per 16x16 tile
#pragma unroll
  for (int j = 0; j < 4; ++j) {
    const int col = n0 + wn * 64 + j * 16 + lm;
    const int s = col >> 9;  // section uniform per block (n0 mult of 128)
    const float* bp = (s == 0) ? b0 : (s == 1 ? b1 : b2);
    const float bias = bp[col & 511];
#pragma unroll
    for (int i = 0; i < 4; ++i) {
      const int row0 = m0 + wm * 64 + i * 16 + quad * 4;
#pragma unroll
      for (int r = 0; r < 4; ++r)
        out[(size_t)(row0 + r) * ldo + col] = (__bf16)(acc[i][j][r] + bias);
    }
  }
}

// ---------------------------------------------------------------------------
// Dilated causal conv as bf16 MFMA GEMM over K0=2048 with row-gathered A.
// Fused epilogue: +bc, relu, +x (fp32), leaky_relu(0.2), fp32 out.
// ---------------------------------------------------------------------------
__global__ __launch_bounds__(256, 2) void conv_gemm_kernel(
    const __bf16* __restrict__ A,   // out2b [16384][512]
    const __bf16* __restrict__ Bt,  // Wc_t  [512][2048]
    const float* __restrict__ bc, const float* __restrict__ x,
    float* __restrict__ out, const __bf16* __restrict__ zeros) {
  __shared__ __align__(16) __bf16 As[128 * 64];
  __shared__ __align__(16) __bf16 Bs[128 * 64];
  const int tid = threadIdx.x;
  const int w = tid >> 6, lane = tid & 63;
  const int wm = w & 1, wn = w >> 1;
  const int lm = lane & 15, quad = lane >> 4;
  const int m0 = blockIdx.y * 128, n0 = blockIdx.x * 128;
  f32x4 acc[4][4] = {};
  for (int k0 = 0; k0 < 4 * Cch; k0 += 64) {
    const int jtap = k0 >> 9;           // constant within a K-tile (64|512)
    const int shift = 4 * jtap - 12;
    const int cin0 = k0 & 511;
#pragma unroll
    for (int it = 0; it < 4; ++it) {
      const int c = w * 4 + it;
      const int e = c * 512 + lane * 8;
      const int row = e >> 6, col = e & 63;
      const int m = m0 + row;
      const __bf16* src = (((m & (Tseq - 1)) + shift) >= 0)
                              ? A + (size_t)(m + shift) * Cch + cin0 + col
                              : zeros + (lane & 7) * 8;
      gld_lds16(src, &As[c * 512]);
      gld_lds16(Bt + (size_t)(n0 + row) * 2048 + k0 + col, &Bs[c * 512]);
    }
    __syncthreads();
#pragma unroll
    for (int ks = 0; ks < 2; ++ks) {
      bf16x8 af[4], bfr[4];
#pragma unroll
      for (int i = 0; i < 4; ++i)
        af[i] = *(const bf16x8*)&As[(wm * 64 + i * 16 + lm) * 64 + ks * 32 + quad * 8];
#pragma unroll
      for (int j = 0; j < 4; ++j)
        bfr[j] = *(const bf16x8*)&Bs[(wn * 64 + j * 16 + lm) * 64 + ks * 32 + quad * 8];
#pragma unroll
      for (int i = 0; i < 4; ++i)
#pragma unroll
        for (int j = 0; j < 4; ++j)
          acc[i][j] = __builtin_amdgcn_mfma_f32_16x16x32_bf16(af[i], bfr[j], acc[i][j], 0, 0, 0);
    }
    __syncthreads();
  }
#pragma unroll
  for (int j = 0; j < 4; ++j) {
    const int col = n0 + wn * 64 + j * 16 + lm;
    const float bias = bc[col];
#pragma unroll
    for (int i = 0; i < 4; ++i) {
      const int row0 = m0 + wm * 64 + i * 16 + quad * 4;
#pragma unroll
      for (int r = 0; r < 4; ++r) {
        float v = acc[i][j][r] + bias;
        v = fmaxf(v, 0.f);
        v += x[(size_t)(row0 + r) * Cch + col];
        out[(size_t)(row0 + r) * Cch + col] = (v >= 0.f) ? v : 0.2f * v;
      }
    }
  }
}

// ---------------------------------------------------------------------------
// Banded attention on bf16 qkv rows [q(512)|k(512)|v(512)], stride 1536.
// One wave per (b,h,t); lane handles dims 2*lane, 2*lane+1. Writes bf16 cat.
// ---------------------------------------------------------------------------
__global__ __launch_bounds__(256) void attn_band_kernel(
    const __bf16* __restrict__ qkv, __bf16* __restrict__ cat) {
  const int w = threadIdx.x >> 6, lane = threadIdx.x & 63;
  const int t = blockIdx.x * 4 + w;
  const int bh = blockIdx.y;
  const int b = bh >> 2, h = bh & 3;
  const int d0 = lane * 2;
  const size_t qbase = ((size_t)(b * Tseq + t)) * Nqkv + h * 128 + d0;
  bf16x2 qv = *(const bf16x2*)(qkv + qbase);
  const float q0 = (float)qv[0], q1 = (float)qv[1];
  const float scale = 0.08838834764831845f;  // 1/sqrt(128)
  float score[7];
#pragma unroll
  for (int i = 0; i < 7; ++i) {
    const int s = t - 3 + i;
    const bool valid = (s >= 0) && (s < Tseq);
    float p = 0.f;
    if (valid) {
      const size_t sb = ((size_t)(b * Tseq + s)) * Nqkv + 512 + h * 128 + d0;
      bf16x2 kv = *(const bf16x2*)(qkv + sb);
      p = q0 * (float)kv[0] + q1 * (float)kv[1];
    }
#pragma unroll
    for (int off = 1; off < 64; off <<= 1) p += __shfl_xor(p, off);
    score[i] = valid ? p * scale : -1e30f;
  }
  float mx = score[0];
#pragma unroll
  for (int i = 1; i < 7; ++i) mx = fmaxf(mx, score[i]);
  float wgt[7], denom = 0.f;
#pragma unroll
  for (int i = 0; i < 7; ++i) {
    wgt[i] = (score[i] > -1e29f) ? expf(score[i] - mx) : 0.f;
    denom += wgt[i];
  }
  const float inv = 1.f / denom;
  float o0 = 0.f, o1 = 0.f;
#pragma unroll
  for (int i = 0; i < 7; ++i) {
    if (wgt[i] != 0.f) {
      const int s = t - 3 + i;
      const size_t sb = ((size_t)(b * Tseq + s)) * Nqkv + 1024 + h * 128 + d0;
      bf16x2 vv = *(const bf16x2*)(qkv + sb);
      o0 += wgt[i] * (float)vv[0];
      o1 += wgt[i] * (float)vv[1];
    }
  }
  bf16x2 o;
  o[0] = (__bf16)(o0 * inv);
  o[1] = (__bf16)(o1 * inv);
  *(bf16x2*)(cat + ((size_t)(b * Tseq + t)) * Cch + h * 128 + d0) = o;
}

// ---------------------------------------------------------------------------
// Cast / pack kernels
// ---------------------------------------------------------------------------
__global__ void cast_x_kernel(const float* __restrict__ x,
                              __bf16* __restrict__ xb) {
  const int i = (blockIdx.x * 256 + threadIdx.x) * 4;
  float4 v = *(const float4*)(x + i);
  bf16x4 o;
  o[0] = (__bf16)v.x; o[1] = (__bf16)v.y; o[2] = (__bf16)v.z; o[3] = (__bf16)v.w;
  *(bf16x4*)(xb + i) = o;
}

// Wqkv_t[n][c]: n in [0,1536): section s=n>>9 (q/k/v), h=(n&511)>>7, kk=n&127
__global__ void pack_wqkv_kernel(const float* __restrict__ Wq,
                                 const float* __restrict__ Wk,
                                 const float* __restrict__ Wv,
                                 __bf16* __restrict__ Wt) {
  const int n = blockIdx.x;
  const int s = n >> 9, hk = n & 511, h = hk >> 7, kk = hk & 127;
  const float* W = (s == 0) ? Wq : (s == 1 ? Wk : Wv);
  const float* src = W + (size_t)h * (512 * 128) + kk;
  __bf16* dst = Wt + (size_t)n * 512;
  for (int c = threadIdx.x; c < 512; c += 256)
    dst[c] = (__bf16)src[(size_t)c * 128];
}

__global__ void pack_wo_kernel(const float* __restrict__ Wo,
                               __bf16* __restrict__ Wt) {
  const int n = blockIdx.x;
  __bf16* dst = Wt + (size_t)n * 512;
  for (int c = threadIdx.x; c < 512; c += 256)
    dst[c] = (__bf16)Wo[(size_t)c * 512 + n];
}

// Wc_t[n][k]: k = j*512+ci, Wc flat (KS,C,C) index k*512+n
__global__ void pack_wc_kernel(const float* __restrict__ Wc,
                               __bf16* __restrict__ Wt) {
  const int n = blockIdx.x;
  __bf16* dst = Wt + (size_t)n * 2048;
  for (int k = threadIdx.x; k < 2048; k += 256)
    dst[k] = (__bf16)Wc[(size_t)k * 512 + n];
}

__global__ void zero_fill_kernel(__bf16* __restrict__ z) {
  const int i = threadIdx.x * 8;
  bf16x8 zero = {};
  *(bf16x8*)(z + i) = zero;
}

// ---------------------------------------------------------------------------
extern "C" void kernel_launch(void* const* d_in, const int* in_sizes, int n_in,
                              void* d_out, int out_size, void* d_ws, size_t ws_size,
                              hipStream_t stream) {
  const float* x  = (const float*)d_in[0];
  const float* Wq = (const float*)d_in[1];
  const float* bq = (const float*)d_in[2];
  const float* Wk = (const float*)d_in[3];
  const float* bk = (const float*)d_in[4];
  const float* Wv = (const float*)d_in[5];
  const float* bv = (const float*)d_in[6];
  const float* Wo = (const float*)d_in[7];
  const float* bo = (const float*)d_in[8];
  const float* Wc = (const float*)d_in[9];
  const float* bc = (const float*)d_in[10];
  float* out = (float*)d_out;

  // Workspace layout (bytes, all 4 KiB aligned):
  char* p = (char*)d_ws;
  __bf16* xb     = (__bf16*)p;                 p += (size_t)Mrows * Cch * 2;   // 16 MiB
  __bf16* qkv    = (__bf16*)p;                 p += (size_t)Mrows * Nqkv * 2;  // 48 MiB
  __bf16* catb   = (__bf16*)p;                 p += (size_t)Mrows * Cch * 2;   // 16 MiB
  __bf16* out2b  = (__bf16*)p;                 p += (size_t)Mrows * Cch * 2;   // 16 MiB
  __bf16* Wqkv_t = (__bf16*)p;                 p += (size_t)Nqkv * Cch * 2;
  __bf16* Wo_t   = (__bf16*)p;                 p += (size_t)Cch * Cch * 2;
  __bf16* Wc_t   = (__bf16*)p;                 p += (size_t)Cch * 2048 * 2;
  __bf16* zeros  = (__bf16*)p;                 p += 4096;

  cast_x_kernel<<<Mrows * Cch / 1024, 256, 0, stream>>>(x, xb);
  pack_wqkv_kernel<<<Nqkv, 256, 0, stream>>>(Wq, Wk, Wv, Wqkv_t);
  pack_wo_kernel<<<Cch, 256, 0, stream>>>(Wo, Wo_t);
  pack_wc_kernel<<<Cch, 256, 0, stream>>>(Wc, Wc_t);
  zero_fill_kernel<<<1, 256, 0, stream>>>(zeros);

  gemm_bt_bf16_kernel<<<dim3(Nqkv / 128, Mrows / 128), 256, 0, stream>>>(
      xb, Cch, Wqkv_t, Cch, bq, bk, bv, qkv, Nqkv);

  attn_band_kernel<<<dim3(Tseq / 4, Bb * 4), 256, 0, stream>>>(qkv, catb);

  gemm_bt_bf16_kernel<<<dim3(Cch / 128, Mrows / 128), 256, 0, stream>>>(
      catb, Cch, Wo_t, Cch, bo, bo, bo, out2b, Cch);

  conv_gemm_kernel<<<dim3(Cch / 128, Mrows / 128), 256, 0, stream>>>(
      out2b, Wc_t, bc, x, out, zeros);
}

// Round 3
// 292.899 us; speedup vs baseline: 3.7567x; 1.0333x over previous
//
#include <hip/hip_runtime.h>
#include <math.h>

#define Bb    8
#define Tseq  2048
#define Cch   512
#define Mrows 16384
#define Nqkv  1536

typedef __bf16 bf16x8 __attribute__((ext_vector_type(8)));
typedef __bf16 bf16x4 __attribute__((ext_vector_type(4)));
typedef float  f32x4  __attribute__((ext_vector_type(4)));

__device__ __forceinline__ void gld_lds16(const void* g, void* l) {
  __builtin_amdgcn_global_load_lds(
      (const __attribute__((address_space(1))) unsigned int*)g,
      (__attribute__((address_space(3))) unsigned int*)l, 16, 0, 0);
}

// XCD-aware remap: blocks with the same m-tile group land on one XCD's L2.
__device__ __forceinline__ void swizzle_mn(int* m0, int* n0) {
  const int NX = gridDim.x;
  const int total = NX * gridDim.y;
  const int lid = blockIdx.y * NX + blockIdx.x;
  const int xcd = lid & 7;
  const int chunk = lid >> 3;
  const int idx = xcd * (total >> 3) + chunk;
  const int mt = idx / NX;
  const int nt = idx - mt * NX;
  *m0 = mt * 128;
  *n0 = nt * 128;
}

// ---------------------------------------------------------------------------
// bf16 MFMA GEMM, B^T input ([N][K]), fp32 bias per 512-col section, bf16 out.
// Tile 128x128, BK=64, 4 waves (2x2), each wave 64x64 via 4x4 MFMA 16x16x32.
// ---------------------------------------------------------------------------
__global__ __launch_bounds__(256, 2) void gemm_bt_bf16_kernel(
    const __bf16* __restrict__ A, int lda,
    const __bf16* __restrict__ Bt, int K,
    const float* __restrict__ b0, const float* __restrict__ b1,
    const float* __restrict__ b2,
    __bf16* __restrict__ out, int ldo) {
  __shared__ __align__(16) __bf16 As[128 * 64];
  __shared__ __align__(16) __bf16 Bs[128 * 64];
  const int tid = threadIdx.x;
  const int w = tid >> 6, lane = tid & 63;
  const int wm = w & 1, wn = w >> 1;
  const int lm = lane & 15, quad = lane >> 4;
  int m0, n0;
  swizzle_mn(&m0, &n0);
  f32x4 acc[4][4] = {};
  for (int k0 = 0; k0 < K; k0 += 64) {
#pragma unroll
    for (int it = 0; it < 4; ++it) {
      const int c = w * 4 + it;
      const int e = c * 512 + lane * 8;
      const int row = e >> 6, col = e & 63;
      gld_lds16(A + (size_t)(m0 + row) * lda + k0 + col, &As[c * 512]);
      gld_lds16(Bt + (size_t)(n0 + row) * K + k0 + col, &Bs[c * 512]);
    }
    __syncthreads();
#pragma unroll
    for (int ks = 0; ks < 2; ++ks) {
      bf16x8 af[4], bfr[4];
#pragma unroll
      for (int i = 0; i < 4; ++i)
        af[i] = *(const bf16x8*)&As[(wm * 64 + i * 16 + lm) * 64 + ks * 32 + quad * 8];
#pragma unroll
      for (int j = 0; j < 4; ++j)
        bfr[j] = *(const bf16x8*)&Bs[(wn * 64 + j * 16 + lm) * 64 + ks * 32 + quad * 8];
#pragma unroll
      for (int i = 0; i < 4; ++i)
#pragma unroll
        for (int j = 0; j < 4; ++j)
          acc[i][j] = __builtin_amdgcn_mfma_f32_16x16x32_bf16(af[i], bfr[j], acc[i][j], 0, 0, 0);
    }
    __syncthreads();
  }
#pragma unroll
  for (int j = 0; j < 4; ++j) {
    const int col = n0 + wn * 64 + j * 16 + lm;
    const int s = col >> 9;
    const float* bp = (s == 0) ? b0 : (s == 1 ? b1 : b2);
    const float bias = bp[col & 511];
#pragma unroll
    for (int i = 0; i < 4; ++i) {
      const int row0 = m0 + wm * 64 + i * 16 + quad * 4;
#pragma unroll
      for (int r = 0; r < 4; ++r)
        out[(size_t)(row0 + r) * ldo + col] = (__bf16)(acc[i][j][r] + bias);
    }
  }
}

// ---------------------------------------------------------------------------
// Wp precompute: for j = blockIdx.z, out_j[n][d] = sum_ci Wc[j,ci,n]*Wo[d,ci]
// A = Wc_t + j*512 (lda 2048), Bt = Wob [d][ci] (ld 512),
// out = Wp_bt + j*512 (ldo 2048). M=N=512 -> grid (4,4,4).
// ---------------------------------------------------------------------------
__global__ __launch_bounds__(256, 2) void gemm_wp_kernel(
    const __bf16* __restrict__ Wc_t, const __bf16* __restrict__ Wob,
    __bf16* __restrict__ Wp_bt) {
  __shared__ __align__(16) __bf16 As[128 * 64];
  __shared__ __align__(16) __bf16 Bs[128 * 64];
  const int tid = threadIdx.x;
  const int w = tid >> 6, lane = tid & 63;
  const int wm = w & 1, wn = w >> 1;
  const int lm = lane & 15, quad = lane >> 4;
  const int m0 = blockIdx.y * 128, n0 = blockIdx.x * 128;
  const __bf16* A = Wc_t + blockIdx.z * 512;
  __bf16* out = Wp_bt + blockIdx.z * 512;
  f32x4 acc[4][4] = {};
  for (int k0 = 0; k0 < 512; k0 += 64) {
#pragma unroll
    for (int it = 0; it < 4; ++it) {
      const int c = w * 4 + it;
      const int e = c * 512 + lane * 8;
      const int row = e >> 6, col = e & 63;
      gld_lds16(A + (size_t)(m0 + row) * 2048 + k0 + col, &As[c * 512]);
      gld_lds16(Wob + (size_t)(n0 + row) * 512 + k0 + col, &Bs[c * 512]);
    }
    __syncthreads();
#pragma unroll
    for (int ks = 0; ks < 2; ++ks) {
      bf16x8 af[4], bfr[4];
#pragma unroll
      for (int i = 0; i < 4; ++i)
        af[i] = *(const bf16x8*)&As[(wm * 64 + i * 16 + lm) * 64 + ks * 32 + quad * 8];
#pragma unroll
      for (int j = 0; j < 4; ++j)
        bfr[j] = *(const bf16x8*)&Bs[(wn * 64 + j * 16 + lm) * 64 + ks * 32 + quad * 8];
#pragma unroll
      for (int i = 0; i < 4; ++i)
#pragma unroll
        for (int j = 0; j < 4; ++j)
          acc[i][j] = __builtin_amdgcn_mfma_f32_16x16x32_bf16(af[i], bfr[j], acc[i][j], 0, 0, 0);
    }
    __syncthreads();
  }
#pragma unroll
  for (int j = 0; j < 4; ++j) {
    const int col = n0 + wn * 64 + j * 16 + lm;
#pragma unroll
    for (int i = 0; i < 4; ++i) {
      const int row0 = m0 + wm * 64 + i * 16 + quad * 4;
#pragma unroll
      for (int r = 0; r < 4; ++r)
        out[(size_t)(row0 + r) * 2048 + col] = (__bf16)(acc[i][j][r]);
    }
  }
}

// ---------------------------------------------------------------------------
// Conv (Wo folded in): out[t,n] via K=2048 GEMM on cat with row gather.
// Epilogue: + (bc + suffix-tap bias) , relu, + x (fp32), leaky_relu(0.2).
// ---------------------------------------------------------------------------
__global__ __launch_bounds__(256, 2) void conv_gemm_kernel(
    const __bf16* __restrict__ A,   // catb [16384][512]
    const __bf16* __restrict__ Bt,  // Wp_bt [512][2048]
    const float* __restrict__ bc, const float* __restrict__ sb,  // sb[4][512]
    const float* __restrict__ x, float* __restrict__ out,
    const __bf16* __restrict__ zeros) {
  __shared__ __align__(16) __bf16 As[128 * 64];
  __shared__ __align__(16) __bf16 Bs[128 * 64];
  const int tid = threadIdx.x;
  const int w = tid >> 6, lane = tid & 63;
  const int wm = w & 1, wn = w >> 1;
  const int lm = lane & 15, quad = lane >> 4;
  int m0, n0;
  swizzle_mn(&m0, &n0);
  f32x4 acc[4][4] = {};
  for (int k0 = 0; k0 < 4 * Cch; k0 += 64) {
    const int jtap = k0 >> 9;
    const int shift = 4 * jtap - 12;
    const int cin0 = k0 & 511;
#pragma unroll
    for (int it = 0; it < 4; ++it) {
      const int c = w * 4 + it;
      const int e = c * 512 + lane * 8;
      const int row = e >> 6, col = e & 63;
      const int m = m0 + row;
      const __bf16* src = (((m & (Tseq - 1)) + shift) >= 0)
                              ? A + (size_t)(m + shift) * Cch + cin0 + col
                              : zeros + (lane & 7) * 8;
      gld_lds16(src, &As[c * 512]);
      gld_lds16(Bt + (size_t)(n0 + row) * 2048 + k0 + col, &Bs[c * 512]);
    }
    __syncthreads();
#pragma unroll
    for (int ks = 0; ks < 2; ++ks) {
      bf16x8 af[4], bfr[4];
#pragma unroll
      for (int i = 0; i < 4; ++i)
        af[i] = *(const bf16x8*)&As[(wm * 64 + i * 16 + lm) * 64 + ks * 32 + quad * 8];
#pragma unroll
      for (int j = 0; j < 4; ++j)
        bfr[j] = *(const bf16x8*)&Bs[(wn * 64 + j * 16 + lm) * 64 + ks * 32 + quad * 8];
#pragma unroll
      for (int i = 0; i < 4; ++i)
#pragma unroll
        for (int j = 0; j < 4; ++j)
          acc[i][j] = __builtin_amdgcn_mfma_f32_16x16x32_bf16(af[i], bfr[j], acc[i][j], 0, 0, 0);
    }
    __syncthreads();
  }
#pragma unroll
  for (int j = 0; j < 4; ++j) {
    const int col = n0 + wn * 64 + j * 16 + lm;
    const float bcv = bc[col];
#pragma unroll
    for (int i = 0; i < 4; ++i) {
      const int row0 = m0 + wm * 64 + i * 16 + quad * 4;
#pragma unroll
      for (int r = 0; r < 4; ++r) {
        const int row = row0 + r;
        const int tl = row & (Tseq - 1);
        int jm = 15 - tl;
        jm = (jm < 0) ? 0 : (jm >> 2);
        float v = acc[i][j][r] + bcv + sb[jm * 512 + col];
        v = fmaxf(v, 0.f);
        v += x[(size_t)row * Cch + col];
        out[(size_t)row * Cch + col] = (v >= 0.f) ? v : 0.2f * v;
      }
    }
  }
}

// ---------------------------------------------------------------------------
// Banded attention: 16-lane groups, bf16x8 loads. grid (T/16, B*H), 256 thr.
// ---------------------------------------------------------------------------
__global__ __launch_bounds__(256) void attn_band_kernel(
    const __bf16* __restrict__ qkv, __bf16* __restrict__ cat) {
  const int tid = threadIdx.x;
  const int tsub = tid >> 4, g = tid & 15;
  const int t = blockIdx.x * 16 + tsub;
  const int bh = blockIdx.y;
  const int b = bh >> 2, h = bh & 3;
  const int d0 = g * 8;
  const size_t base = ((size_t)(b * Tseq + t)) * Nqkv + h * 128 + d0;
  bf16x8 qv = *(const bf16x8*)(qkv + base);
  const float scale = 0.08838834764831845f;  // 1/sqrt(128)
  float score[7];
#pragma unroll
  for (int i = 0; i < 7; ++i) {
    const int s = t - 3 + i;
    const bool valid = (s >= 0) && (s < Tseq);
    float p = 0.f;
    if (valid) {
      bf16x8 kv = *(const bf16x8*)(qkv + base + (size_t)(i - 3) * Nqkv + 512);
#pragma unroll
      for (int e = 0; e < 8; ++e) p += (float)qv[e] * (float)kv[e];
    }
    p += __shfl_xor(p, 1);
    p += __shfl_xor(p, 2);
    p += __shfl_xor(p, 4);
    p += __shfl_xor(p, 8);
    score[i] = valid ? p * scale : -1e30f;
  }
  float mx = score[0];
#pragma unroll
  for (int i = 1; i < 7; ++i) mx = fmaxf(mx, score[i]);
  float wgt[7], denom = 0.f;
#pragma unroll
  for (int i = 0; i < 7; ++i) {
    wgt[i] = (score[i] > -1e29f) ? expf(score[i] - mx) : 0.f;
    denom += wgt[i];
  }
  const float inv = 1.f / denom;
  float o[8] = {};
#pragma unroll
  for (int i = 0; i < 7; ++i) {
    if (wgt[i] != 0.f) {
      bf16x8 vv = *(const bf16x8*)(qkv + base + (size_t)(i - 3) * Nqkv + 1024);
#pragma unroll
      for (int e = 0; e < 8; ++e) o[e] += wgt[i] * (float)vv[e];
    }
  }
  bf16x8 ov;
#pragma unroll
  for (int e = 0; e < 8; ++e) ov[e] = (__bf16)(o[e] * inv);
  *(bf16x8*)(cat + ((size_t)(b * Tseq + t)) * Cch + h * 128 + d0) = ov;
}

// ---------------------------------------------------------------------------
// Pack / cast kernels
// ---------------------------------------------------------------------------
__global__ void cast_x_kernel(const float* __restrict__ x,
                              __bf16* __restrict__ xb) {
  const int i = (blockIdx.x * 256 + threadIdx.x) * 4;
  float4 v = *(const float4*)(x + i);
  bf16x4 o;
  o[0] = (__bf16)v.x; o[1] = (__bf16)v.y; o[2] = (__bf16)v.z; o[3] = (__bf16)v.w;
  *(bf16x4*)(xb + i) = o;
}

__global__ void cast_wo_kernel(const float* __restrict__ Wo,
                               __bf16* __restrict__ Wob) {
  const int i = (blockIdx.x * 256 + threadIdx.x) * 4;
  float4 v = *(const float4*)(Wo + i);
  bf16x4 o;
  o[0] = (__bf16)v.x; o[1] = (__bf16)v.y; o[2] = (__bf16)v.z; o[3] = (__bf16)v.w;
  *(bf16x4*)(Wob + i) = o;
}

// Generic 32x32 LDS transpose-cast: src fp32 [R][C] -> dst bf16 [C][R]
__global__ void transpose_wc_kernel(const float* __restrict__ src,
                                    __bf16* __restrict__ dst) {
  const int R = 2048, C = 512;
  __shared__ float s[32][33];
  const int tx = threadIdx.x & 31, ty = threadIdx.x >> 5;
  const int c0 = blockIdx.x * 32, r0 = blockIdx.y * 32;
#pragma unroll
  for (int rr = 0; rr < 4; ++rr)
    s[ty + rr * 8][tx] = src[(size_t)(r0 + ty + rr * 8) * C + c0 + tx];
  __syncthreads();
#pragma unroll
  for (int rr = 0; rr < 4; ++rr)
    dst[(size_t)(c0 + ty + rr * 8) * R + r0 + tx] = (__bf16)s[tx][ty + rr * 8];
}

// Wqkv pack: z = (s,h); transpose src[512][128] -> dst[128][512]
__global__ void transpose_wqkv_kernel(const float* __restrict__ Wq,
                                      const float* __restrict__ Wk,
                                      const float* __restrict__ Wv,
                                      __bf16* __restrict__ Wt) {
  __shared__ float s[32][33];
  const int z = blockIdx.z, sgrp = z >> 2, h = z & 3;
  const float* src = ((sgrp == 0) ? Wq : (sgrp == 1) ? Wk : Wv) + h * (512 * 128);
  __bf16* dst = Wt + (size_t)z * 128 * 512;
  const int tx = threadIdx.x & 31, ty = threadIdx.x >> 5;
  const int c0 = blockIdx.x * 32, r0 = blockIdx.y * 32;
#pragma unroll
  for (int rr = 0; rr < 4; ++rr)
    s[ty + rr * 8][tx] = src[(size_t)(r0 + ty + rr * 8) * 128 + c0 + tx];
  __syncthreads();
#pragma unroll
  for (int rr = 0; rr < 4; ++rr)
    dst[(size_t)(c0 + ty + rr * 8) * 512 + r0 + tx] = (__bf16)s[tx][ty + rr * 8];
}

// Per-tap conv bias suffix sums: sb[j][n] = sum_{j'>=j} sum_ci bo[ci]*Wc[j',ci,n]
__global__ void bias_taps_kernel(const float* __restrict__ bo,
                                 const float* __restrict__ Wc,
                                 float* __restrict__ sb) {
  const int n = blockIdx.x * 256 + threadIdx.x;
  float bj[4] = {};
#pragma unroll
  for (int j = 0; j < 4; ++j)
    for (int ci = 0; ci < 512; ++ci)
      bj[j] += bo[ci] * Wc[(size_t)(j * 512 + ci) * 512 + n];
  float suf = 0.f;
  for (int j = 3; j >= 0; --j) {
    suf += bj[j];
    sb[j * 512 + n] = suf;
  }
}

__global__ void zero_fill_kernel(__bf16* __restrict__ z) {
  bf16x8 zero = {};
  *(bf16x8*)(z + threadIdx.x * 8) = zero;
}

// ---------------------------------------------------------------------------
extern "C" void kernel_launch(void* const* d_in, const int* in_sizes, int n_in,
                              void* d_out, int out_size, void* d_ws, size_t ws_size,
                              hipStream_t stream) {
  const float* x  = (const float*)d_in[0];
  const float* Wq = (const float*)d_in[1];
  const float* bq = (const float*)d_in[2];
  const float* Wk = (const float*)d_in[3];
  const float* bk = (const float*)d_in[4];
  const float* Wv = (const float*)d_in[5];
  const float* bv = (const float*)d_in[6];
  const float* Wo = (const float*)d_in[7];
  const float* bo = (const float*)d_in[8];
  const float* Wc = (const float*)d_in[9];
  const float* bc = (const float*)d_in[10];
  float* out = (float*)d_out;

  char* p = (char*)d_ws;
  __bf16* xb     = (__bf16*)p;  p += (size_t)Mrows * Cch * 2;    // 16 MiB
  __bf16* qkv    = (__bf16*)p;  p += (size_t)Mrows * Nqkv * 2;   // 48 MiB
  __bf16* catb   = (__bf16*)p;  p += (size_t)Mrows * Cch * 2;    // 16 MiB
  __bf16* Wqkv_t = (__bf16*)p;  p += (size_t)Nqkv * Cch * 2;     // 1.5 MiB
  __bf16* Wc_t   = (__bf16*)p;  p += (size_t)Cch * 2048 * 2;     // 2 MiB
  __bf16* Wob    = (__bf16*)p;  p += (size_t)Cch * Cch * 2;      // 0.5 MiB
  __bf16* Wp_bt  = (__bf16*)p;  p += (size_t)Cch * 2048 * 2;     // 2 MiB
  float*  sb     = (float*)p;   p += 4 * Cch * 4;                // 8 KiB
  __bf16* zeros  = (__bf16*)p;  p += 4096;

  cast_x_kernel<<<Mrows * Cch / 1024, 256, 0, stream>>>(x, xb);
  transpose_wqkv_kernel<<<dim3(4, 16, 12), 256, 0, stream>>>(Wq, Wk, Wv, Wqkv_t);
  transpose_wc_kernel<<<dim3(16, 64), 256, 0, stream>>>(Wc, Wc_t);
  cast_wo_kernel<<<Cch * Cch / 1024, 256, 0, stream>>>(Wo, Wob);
  bias_taps_kernel<<<2, 256, 0, stream>>>(bo, Wc, sb);
  zero_fill_kernel<<<1, 256, 0, stream>>>(zeros);

  // Wp[j] = Wo @ Wc[j]  (folds the head-combine GEMM into the conv weights)
  gemm_wp_kernel<<<dim3(4, 4, 4), 256, 0, stream>>>(Wc_t, Wob, Wp_bt);

  gemm_bt_bf16_kernel<<<dim3(Nqkv / 128, Mrows / 128), 256, 0, stream>>>(
      xb, Cch, Wqkv_t, Cch, bq, bk, bv, qkv, Nqkv);

  attn_band_kernel<<<dim3(Tseq / 16, Bb * 4), 256, 0, stream>>>(qkv, catb);

  conv_gemm_kernel<<<dim3(Cch / 128, Mrows / 128), 256, 0, stream>>>(
      catb, Wp_bt, bc, sb, x, out, zeros);
}

// Round 4
// 276.227 us; speedup vs baseline: 3.9834x; 1.0604x over previous
//
#include <hip/hip_runtime.h>
#include <math.h>

#define Bb    8
#define Tseq  2048
#define Cch   512
#define Mrows 16384
#define Nqkv  1536

typedef __bf16 bf16x8 __attribute__((ext_vector_type(8)));
typedef __bf16 bf16x4 __attribute__((ext_vector_type(4)));
typedef float  f32x4  __attribute__((ext_vector_type(4)));

__device__ __forceinline__ void gld_lds16(const void* g, void* l) {
  __builtin_amdgcn_global_load_lds(
      (const __attribute__((address_space(1))) unsigned int*)g,
      (__attribute__((address_space(3))) unsigned int*)l, 16, 0, 0);
}

// XCD-aware remap: blocks with the same m-tile group land on one XCD's L2.
__device__ __forceinline__ void swizzle_mn(int* m0, int* n0) {
  const int NX = gridDim.x;
  const int total = NX * gridDim.y;
  const int lid = blockIdx.y * NX + blockIdx.x;
  const int xcd = lid & 7;
  const int chunk = lid >> 3;
  const int idx = xcd * (total >> 3) + chunk;
  const int mt = idx / NX;
  const int nt = idx - mt * NX;
  *m0 = mt * 128;
  *n0 = nt * 128;
}

// ---------------------------------------------------------------------------
// bf16 MFMA GEMM, B^T input ([N][K]), fp32 bias per 512-col section, bf16 out.
// Tile 128x128, BK=64, 4 waves (2x2), each wave 64x64 via 4x4 MFMA 16x16x32.
// ---------------------------------------------------------------------------
__global__ __launch_bounds__(256, 2) void gemm_bt_bf16_kernel(
    const __bf16* __restrict__ A, int lda,
    const __bf16* __restrict__ Bt, int K,
    const float* __restrict__ b0, const float* __restrict__ b1,
    const float* __restrict__ b2,
    __bf16* __restrict__ out, int ldo) {
  __shared__ __align__(16) __bf16 As[128 * 64];
  __shared__ __align__(16) __bf16 Bs[128 * 64];
  const int tid = threadIdx.x;
  const int w = tid >> 6, lane = tid & 63;
  const int wm = w & 1, wn = w >> 1;
  const int lm = lane & 15, quad = lane >> 4;
  int m0, n0;
  swizzle_mn(&m0, &n0);
  f32x4 acc[4][4] = {};
  for (int k0 = 0; k0 < K; k0 += 64) {
#pragma unroll
    for (int it = 0; it < 4; ++it) {
      const int c = w * 4 + it;
      const int e = c * 512 + lane * 8;
      const int row = e >> 6, col = e & 63;
      gld_lds16(A + (size_t)(m0 + row) * lda + k0 + col, &As[c * 512]);
      gld_lds16(Bt + (size_t)(n0 + row) * K + k0 + col, &Bs[c * 512]);
    }
    __syncthreads();
#pragma unroll
    for (int ks = 0; ks < 2; ++ks) {
      bf16x8 af[4], bfr[4];
#pragma unroll
      for (int i = 0; i < 4; ++i)
        af[i] = *(const bf16x8*)&As[(wm * 64 + i * 16 + lm) * 64 + ks * 32 + quad * 8];
#pragma unroll
      for (int j = 0; j < 4; ++j)
        bfr[j] = *(const bf16x8*)&Bs[(wn * 64 + j * 16 + lm) * 64 + ks * 32 + quad * 8];
#pragma unroll
      for (int i = 0; i < 4; ++i)
#pragma unroll
        for (int j = 0; j < 4; ++j)
          acc[i][j] = __builtin_amdgcn_mfma_f32_16x16x32_bf16(af[i], bfr[j], acc[i][j], 0, 0, 0);
    }
    __syncthreads();
  }
#pragma unroll
  for (int j = 0; j < 4; ++j) {
    const int col = n0 + wn * 64 + j * 16 + lm;
    const int s = col >> 9;
    const float* bp = (s == 0) ? b0 : (s == 1 ? b1 : b2);
    const float bias = bp[col & 511];
#pragma unroll
    for (int i = 0; i < 4; ++i) {
      const int row0 = m0 + wm * 64 + i * 16 + quad * 4;
#pragma unroll
      for (int r = 0; r < 4; ++r)
        out[(size_t)(row0 + r) * ldo + col] = (__bf16)(acc[i][j][r] + bias);
    }
  }
}

// ---------------------------------------------------------------------------
// Wp precompute: for j = blockIdx.z, out_j[n][d] = sum_ci Wc[j,ci,n]*Wo[d,ci]
// ---------------------------------------------------------------------------
__global__ __launch_bounds__(256, 2) void gemm_wp_kernel(
    const __bf16* __restrict__ Wc_t, const __bf16* __restrict__ Wob,
    __bf16* __restrict__ Wp_bt) {
  __shared__ __align__(16) __bf16 As[128 * 64];
  __shared__ __align__(16) __bf16 Bs[128 * 64];
  const int tid = threadIdx.x;
  const int w = tid >> 6, lane = tid & 63;
  const int wm = w & 1, wn = w >> 1;
  const int lm = lane & 15, quad = lane >> 4;
  const int m0 = blockIdx.y * 128, n0 = blockIdx.x * 128;
  const __bf16* A = Wc_t + blockIdx.z * 512;
  __bf16* out = Wp_bt + blockIdx.z * 512;
  f32x4 acc[4][4] = {};
  for (int k0 = 0; k0 < 512; k0 += 64) {
#pragma unroll
    for (int it = 0; it < 4; ++it) {
      const int c = w * 4 + it;
      const int e = c * 512 + lane * 8;
      const int row = e >> 6, col = e & 63;
      gld_lds16(A + (size_t)(m0 + row) * 2048 + k0 + col, &As[c * 512]);
      gld_lds16(Wob + (size_t)(n0 + row) * 512 + k0 + col, &Bs[c * 512]);
    }
    __syncthreads();
#pragma unroll
    for (int ks = 0; ks < 2; ++ks) {
      bf16x8 af[4], bfr[4];
#pragma unroll
      for (int i = 0; i < 4; ++i)
        af[i] = *(const bf16x8*)&As[(wm * 64 + i * 16 + lm) * 64 + ks * 32 + quad * 8];
#pragma unroll
      for (int j = 0; j < 4; ++j)
        bfr[j] = *(const bf16x8*)&Bs[(wn * 64 + j * 16 + lm) * 64 + ks * 32 + quad * 8];
#pragma unroll
      for (int i = 0; i < 4; ++i)
#pragma unroll
        for (int j = 0; j < 4; ++j)
          acc[i][j] = __builtin_amdgcn_mfma_f32_16x16x32_bf16(af[i], bfr[j], acc[i][j], 0, 0, 0);
    }
    __syncthreads();
  }
#pragma unroll
  for (int j = 0; j < 4; ++j) {
    const int col = n0 + wn * 64 + j * 16 + lm;
#pragma unroll
    for (int i = 0; i < 4; ++i) {
      const int row0 = m0 + wm * 64 + i * 16 + quad * 4;
#pragma unroll
      for (int r = 0; r < 4; ++r)
        out[(size_t)(row0 + r) * 2048 + col] = (__bf16)(acc[i][j][r]);
    }
  }
}

// ---------------------------------------------------------------------------
// Conv (Wo folded): K=2048 GEMM on cat with row gather. BK=128 (64 KiB LDS):
// grid is 512 blocks (2/CU residency cap), so bigger K-tile costs no
// occupancy and halves barrier count (64 MFMA per K-tile).
// Epilogue: + (bc + suffix-tap bias), relu, + x (fp32), leaky_relu(0.2).
// ---------------------------------------------------------------------------
__global__ __launch_bounds__(256, 2) void conv_gemm_kernel(
    const __bf16* __restrict__ A,   // catb [16384][512]
    const __bf16* __restrict__ Bt,  // Wp_bt [512][2048]
    const float* __restrict__ bc, const float* __restrict__ sb,  // sb[4][512]
    const float* __restrict__ x, float* __restrict__ out,
    const __bf16* __restrict__ zeros) {
  __shared__ __align__(16) __bf16 As[128 * 128];
  __shared__ __align__(16) __bf16 Bs[128 * 128];
  const int tid = threadIdx.x;
  const int w = tid >> 6, lane = tid & 63;
  const int wm = w & 1, wn = w >> 1;
  const int lm = lane & 15, quad = lane >> 4;
  int m0, n0;
  swizzle_mn(&m0, &n0);
  f32x4 acc[4][4] = {};
  for (int k0 = 0; k0 < 4 * Cch; k0 += 128) {
    const int jtap = k0 >> 9;          // 128 | 512 -> tap constant per K-tile
    const int shift = 4 * jtap - 12;
    const int cin0 = k0 & 511;
#pragma unroll
    for (int it = 0; it < 8; ++it) {
      const int c = w * 8 + it;           // chunk 0..31 (4 rows each)
      const int e = c * 512 + lane * 8;   // elem offset in 128x128 tile
      const int row = e >> 7, col = e & 127;
      const int m = m0 + row;
      const __bf16* srcA = (((m & (Tseq - 1)) + shift) >= 0)
                               ? A + (size_t)(m + shift) * Cch + cin0 + col
                               : zeros + lane * 8;
      gld_lds16(srcA, &As[c * 512]);
      gld_lds16(Bt + (size_t)(n0 + row) * 2048 + k0 + col, &Bs[c * 512]);
    }
    __syncthreads();
#pragma unroll
    for (int ks = 0; ks < 4; ++ks) {
      bf16x8 af[4], bfr[4];
#pragma unroll
      for (int i = 0; i < 4; ++i)
        af[i] = *(const bf16x8*)&As[(wm * 64 + i * 16 + lm) * 128 + ks * 32 + quad * 8];
#pragma unroll
      for (int j = 0; j < 4; ++j)
        bfr[j] = *(const bf16x8*)&Bs[(wn * 64 + j * 16 + lm) * 128 + ks * 32 + quad * 8];
#pragma unroll
      for (int i = 0; i < 4; ++i)
#pragma unroll
        for (int j = 0; j < 4; ++j)
          acc[i][j] = __builtin_amdgcn_mfma_f32_16x16x32_bf16(af[i], bfr[j], acc[i][j], 0, 0, 0);
    }
    __syncthreads();
  }
#pragma unroll
  for (int j = 0; j < 4; ++j) {
    const int col = n0 + wn * 64 + j * 16 + lm;
    const float bcv = bc[col];
#pragma unroll
    for (int i = 0; i < 4; ++i) {
      const int row0 = m0 + wm * 64 + i * 16 + quad * 4;
#pragma unroll
      for (int r = 0; r < 4; ++r) {
        const int row = row0 + r;
        const int tl = row & (Tseq - 1);
        int jm = 15 - tl;
        jm = (jm < 0) ? 0 : (jm >> 2);
        float v = acc[i][j][r] + bcv + sb[jm * 512 + col];
        v = fmaxf(v, 0.f);
        v += x[(size_t)row * Cch + col];
        out[(size_t)row * Cch + col] = (v >= 0.f) ? v : 0.2f * v;
      }
    }
  }
}

// ---------------------------------------------------------------------------
// Banded attention: 16-lane groups, bf16x8 loads. grid (T/16, B*H), 256 thr.
// ---------------------------------------------------------------------------
__global__ __launch_bounds__(256) void attn_band_kernel(
    const __bf16* __restrict__ qkv, __bf16* __restrict__ cat) {
  const int tid = threadIdx.x;
  const int tsub = tid >> 4, g = tid & 15;
  const int t = blockIdx.x * 16 + tsub;
  const int bh = blockIdx.y;
  const int b = bh >> 2, h = bh & 3;
  const int d0 = g * 8;
  const size_t base = ((size_t)(b * Tseq + t)) * Nqkv + h * 128 + d0;
  bf16x8 qv = *(const bf16x8*)(qkv + base);
  const float scale = 0.08838834764831845f;  // 1/sqrt(128)
  float score[7];
#pragma unroll
  for (int i = 0; i < 7; ++i) {
    const int s = t - 3 + i;
    const bool valid = (s >= 0) && (s < Tseq);
    float p = 0.f;
    if (valid) {
      bf16x8 kv = *(const bf16x8*)(qkv + base + (size_t)(i - 3) * Nqkv + 512);
#pragma unroll
      for (int e = 0; e < 8; ++e) p += (float)qv[e] * (float)kv[e];
    }
    p += __shfl_xor(p, 1);
    p += __shfl_xor(p, 2);
    p += __shfl_xor(p, 4);
    p += __shfl_xor(p, 8);
    score[i] = valid ? p * scale : -1e30f;
  }
  float mx = score[0];
#pragma unroll
  for (int i = 1; i < 7; ++i) mx = fmaxf(mx, score[i]);
  float wgt[7], denom = 0.f;
#pragma unroll
  for (int i = 0; i < 7; ++i) {
    wgt[i] = (score[i] > -1e29f) ? expf(score[i] - mx) : 0.f;
    denom += wgt[i];
  }
  const float inv = 1.f / denom;
  float o[8] = {};
#pragma unroll
  for (int i = 0; i < 7; ++i) {
    if (wgt[i] != 0.f) {
      bf16x8 vv = *(const bf16x8*)(qkv + base + (size_t)(i - 3) * Nqkv + 1024);
#pragma unroll
      for (int e = 0; e < 8; ++e) o[e] += wgt[i] * (float)vv[e];
    }
  }
  bf16x8 ov;
#pragma unroll
  for (int e = 0; e < 8; ++e) ov[e] = (__bf16)(o[e] * inv);
  *(bf16x8*)(cat + ((size_t)(b * Tseq + t)) * Cch + h * 128 + d0) = ov;
}

// ---------------------------------------------------------------------------
// Pack / cast kernels
// ---------------------------------------------------------------------------
__global__ void cast_x_kernel(const float* __restrict__ x,
                              __bf16* __restrict__ xb) {
  const int i = (blockIdx.x * 256 + threadIdx.x) * 4;
  float4 v = *(const float4*)(x + i);
  bf16x4 o;
  o[0] = (__bf16)v.x; o[1] = (__bf16)v.y; o[2] = (__bf16)v.z; o[3] = (__bf16)v.w;
  *(bf16x4*)(xb + i) = o;
}

__global__ void cast_wo_kernel(const float* __restrict__ Wo,
                               __bf16* __restrict__ Wob) {
  const int i = (blockIdx.x * 256 + threadIdx.x) * 4;
  float4 v = *(const float4*)(Wo + i);
  bf16x4 o;
  o[0] = (__bf16)v.x; o[1] = (__bf16)v.y; o[2] = (__bf16)v.z; o[3] = (__bf16)v.w;
  *(bf16x4*)(Wob + i) = o;
}

// 32x32 LDS transpose-cast: src fp32 [2048][512] -> dst bf16 [512][2048]
__global__ void transpose_wc_kernel(const float* __restrict__ src,
                                    __bf16* __restrict__ dst) {
  const int R = 2048, C = 512;
  __shared__ float s[32][33];
  const int tx = threadIdx.x & 31, ty = threadIdx.x >> 5;
  const int c0 = blockIdx.x * 32, r0 = blockIdx.y * 32;
#pragma unroll
  for (int rr = 0; rr < 4; ++rr)
    s[ty + rr * 8][tx] = src[(size_t)(r0 + ty + rr * 8) * C + c0 + tx];
  __syncthreads();
#pragma unroll
  for (int rr = 0; rr < 4; ++rr)
    dst[(size_t)(c0 + ty + rr * 8) * R + r0 + tx] = (__bf16)s[tx][ty + rr * 8];
}

// Wqkv pack: z = (s,h); transpose src[512][128] -> dst[128][512]
__global__ void transpose_wqkv_kernel(const float* __restrict__ Wq,
                                      const float* __restrict__ Wk,
                                      const float* __restrict__ Wv,
                                      __bf16* __restrict__ Wt) {
  __shared__ float s[32][33];
  const int z = blockIdx.z, sgrp = z >> 2, h = z & 3;
  const float* src = ((sgrp == 0) ? Wq : (sgrp == 1) ? Wk : Wv) + h * (512 * 128);
  __bf16* dst = Wt + (size_t)z * 128 * 512;
  const int tx = threadIdx.x & 31, ty = threadIdx.x >> 5;
  const int c0 = blockIdx.x * 32, r0 = blockIdx.y * 32;
#pragma unroll
  for (int rr = 0; rr < 4; ++rr)
    s[ty + rr * 8][tx] = src[(size_t)(r0 + ty + rr * 8) * 128 + c0 + tx];
  __syncthreads();
#pragma unroll
  for (int rr = 0; rr < 4; ++rr)
    dst[(size_t)(c0 + ty + rr * 8) * 512 + r0 + tx] = (__bf16)s[tx][ty + rr * 8];
}

// Per-tap bias partials: bj[j][n] = sum_ci bo[ci]*Wc[j,ci,n].
// grid (4 j, 2 nc) x 256 thr; reads coalesced across n for each ci.
__global__ void bias_tap_partial_kernel(const float* __restrict__ bo,
                                        const float* __restrict__ Wc,
                                        float* __restrict__ bj) {
  const int j = blockIdx.x;
  const int n = blockIdx.y * 256 + threadIdx.x;
  const float* base = Wc + (size_t)j * 512 * 512 + n;
  float acc = 0.f;
#pragma unroll 8
  for (int ci = 0; ci < 512; ++ci) acc += bo[ci] * base[(size_t)ci * 512];
  bj[j * 512 + n] = acc;
}

// Suffix sums: sb[j][n] = sum_{j'>=j} bj[j'][n]
__global__ void bias_tap_suffix_kernel(const float* __restrict__ bj,
                                       float* __restrict__ sb) {
  const int n = blockIdx.x * 256 + threadIdx.x;
  float suf = 0.f;
  for (int j = 3; j >= 0; --j) {
    suf += bj[j * 512 + n];
    sb[j * 512 + n] = suf;
  }
}

__global__ void zero_fill_kernel(__bf16* __restrict__ z) {
  bf16x8 zero = {};
  *(bf16x8*)(z + threadIdx.x * 8) = zero;
}

// ---------------------------------------------------------------------------
extern "C" void kernel_launch(void* const* d_in, const int* in_sizes, int n_in,
                              void* d_out, int out_size, void* d_ws, size_t ws_size,
                              hipStream_t stream) {
  const float* x  = (const float*)d_in[0];
  const float* Wq = (const float*)d_in[1];
  const float* bq = (const float*)d_in[2];
  const float* Wk = (const float*)d_in[3];
  const float* bk = (const float*)d_in[4];
  const float* Wv = (const float*)d_in[5];
  const float* bv = (const float*)d_in[6];
  const float* Wo = (const float*)d_in[7];
  const float* bo = (const float*)d_in[8];
  const float* Wc = (const float*)d_in[9];
  const float* bc = (const float*)d_in[10];
  float* out = (float*)d_out;

  char* p = (char*)d_ws;
  __bf16* xb     = (__bf16*)p;  p += (size_t)Mrows * Cch * 2;    // 16 MiB
  __bf16* qkv    = (__bf16*)p;  p += (size_t)Mrows * Nqkv * 2;   // 48 MiB
  __bf16* catb   = (__bf16*)p;  p += (size_t)Mrows * Cch * 2;    // 16 MiB
  __bf16* Wqkv_t = (__bf16*)p;  p += (size_t)Nqkv * Cch * 2;     // 1.5 MiB
  __bf16* Wc_t   = (__bf16*)p;  p += (size_t)Cch * 2048 * 2;     // 2 MiB
  __bf16* Wob    = (__bf16*)p;  p += (size_t)Cch * Cch * 2;      // 0.5 MiB
  __bf16* Wp_bt  = (__bf16*)p;  p += (size_t)Cch * 2048 * 2;     // 2 MiB
  float*  sb     = (float*)p;   p += 4 * Cch * 4;                // 8 KiB
  float*  bj     = (float*)p;   p += 4 * Cch * 4;                // 8 KiB
  __bf16* zeros  = (__bf16*)p;  p += 4096;

  cast_x_kernel<<<Mrows * Cch / 1024, 256, 0, stream>>>(x, xb);
  transpose_wqkv_kernel<<<dim3(4, 16, 12), 256, 0, stream>>>(Wq, Wk, Wv, Wqkv_t);
  transpose_wc_kernel<<<dim3(16, 64), 256, 0, stream>>>(Wc, Wc_t);
  cast_wo_kernel<<<Cch * Cch / 1024, 256, 0, stream>>>(Wo, Wob);
  bias_tap_partial_kernel<<<dim3(4, 2), 256, 0, stream>>>(bo, Wc, bj);
  bias_tap_suffix_kernel<<<2, 256, 0, stream>>>(bj, sb);
  zero_fill_kernel<<<1, 256, 0, stream>>>(zeros);

  // Wp[j] = Wo @ Wc[j]  (folds the head-combine GEMM into the conv weights)
  gemm_wp_kernel<<<dim3(4, 4, 4), 256, 0, stream>>>(Wc_t, Wob, Wp_bt);

  gemm_bt_bf16_kernel<<<dim3(Nqkv / 128, Mrows / 128), 256, 0, stream>>>(
      xb, Cch, Wqkv_t, Cch, bq, bk, bv, qkv, Nqkv);

  attn_band_kernel<<<dim3(Tseq / 16, Bb * 4), 256, 0, stream>>>(qkv, catb);

  conv_gemm_kernel<<<dim3(Cch / 128, Mrows / 128), 256, 0, stream>>>(
      catb, Wp_bt, bc, sb, x, out, zeros);
}

// Round 5
// 232.716 us; speedup vs baseline: 4.7282x; 1.1870x over previous
//
#include <hip/hip_runtime.h>
#include <math.h>

#define Bb    8
#define Tseq  2048
#define Cch   512
#define Mrows 16384
#define Nqkv  1536

typedef __bf16 bf16x8 __attribute__((ext_vector_type(8)));
typedef __bf16 bf16x4 __attribute__((ext_vector_type(4)));
typedef float  f32x4  __attribute__((ext_vector_type(4)));

__device__ __forceinline__ void gld_lds16(const void* g, void* l) {
  __builtin_amdgcn_global_load_lds(
      (const __attribute__((address_space(1))) unsigned int*)g,
      (__attribute__((address_space(3))) unsigned int*)l, 16, 0, 0);
}

// XCD-aware remap: blocks with the same m-tile group land on one XCD's L2.
__device__ __forceinline__ void swizzle_mn(int* m0, int* n0) {
  const int NX = gridDim.x;
  const int total = NX * gridDim.y;
  const int lid = blockIdx.y * NX + blockIdx.x;
  const int xcd = lid & 7;
  const int chunk = lid >> 3;
  const int idx = xcd * (total >> 3) + chunk;
  const int mt = idx / NX;
  const int nt = idx - mt * NX;
  *m0 = mt * 128;
  *n0 = nt * 128;
}

// ---------------------------------------------------------------------------
// bf16 MFMA GEMM, B^T input ([N][K]), fp32 bias per 512-col section, bf16 out.
// Tile 128x128, BK=64, 4 waves (2x2), each wave 64x64 via 4x4 MFMA 16x16x32.
// ---------------------------------------------------------------------------
__global__ __launch_bounds__(256, 2) void gemm_bt_bf16_kernel(
    const __bf16* __restrict__ A, int lda,
    const __bf16* __restrict__ Bt, int K,
    const float* __restrict__ b0, const float* __restrict__ b1,
    const float* __restrict__ b2,
    __bf16* __restrict__ out, int ldo) {
  __shared__ __align__(16) __bf16 As[128 * 64];
  __shared__ __align__(16) __bf16 Bs[128 * 64];
  const int tid = threadIdx.x;
  const int w = tid >> 6, lane = tid & 63;
  const int wm = w & 1, wn = w >> 1;
  const int lm = lane & 15, quad = lane >> 4;
  int m0, n0;
  swizzle_mn(&m0, &n0);
  f32x4 acc[4][4] = {};
  for (int k0 = 0; k0 < K; k0 += 64) {
#pragma unroll
    for (int it = 0; it < 4; ++it) {
      const int c = w * 4 + it;
      const int e = c * 512 + lane * 8;
      const int row = e >> 6, col = e & 63;
      gld_lds16(A + (size_t)(m0 + row) * lda + k0 + col, &As[c * 512]);
      gld_lds16(Bt + (size_t)(n0 + row) * K + k0 + col, &Bs[c * 512]);
    }
    __syncthreads();
#pragma unroll
    for (int ks = 0; ks < 2; ++ks) {
      bf16x8 af[4], bfr[4];
#pragma unroll
      for (int i = 0; i < 4; ++i)
        af[i] = *(const bf16x8*)&As[(wm * 64 + i * 16 + lm) * 64 + ks * 32 + quad * 8];
#pragma unroll
      for (int j = 0; j < 4; ++j)
        bfr[j] = *(const bf16x8*)&Bs[(wn * 64 + j * 16 + lm) * 64 + ks * 32 + quad * 8];
#pragma unroll
      for (int i = 0; i < 4; ++i)
#pragma unroll
        for (int j = 0; j < 4; ++j)
          acc[i][j] = __builtin_amdgcn_mfma_f32_16x16x32_bf16(af[i], bfr[j], acc[i][j], 0, 0, 0);
    }
    __syncthreads();
  }
#pragma unroll
  for (int j = 0; j < 4; ++j) {
    const int col = n0 + wn * 64 + j * 16 + lm;
    const int s = col >> 9;
    const float* bp = (s == 0) ? b0 : (s == 1 ? b1 : b2);
    const float bias = bp[col & 511];
#pragma unroll
    for (int i = 0; i < 4; ++i) {
      const int row0 = m0 + wm * 64 + i * 16 + quad * 4;
#pragma unroll
      for (int r = 0; r < 4; ++r)
        out[(size_t)(row0 + r) * ldo + col] = (__bf16)(acc[i][j][r] + bias);
    }
  }
}

// ---------------------------------------------------------------------------
// Wp precompute: for j = blockIdx.z, out_j[n][d] = sum_ci Wc[j,ci,n]*Wo[d,ci]
// ---------------------------------------------------------------------------
__global__ __launch_bounds__(256, 2) void gemm_wp_kernel(
    const __bf16* __restrict__ Wc_t, const __bf16* __restrict__ Wob,
    __bf16* __restrict__ Wp_bt) {
  __shared__ __align__(16) __bf16 As[128 * 64];
  __shared__ __align__(16) __bf16 Bs[128 * 64];
  const int tid = threadIdx.x;
  const int w = tid >> 6, lane = tid & 63;
  const int wm = w & 1, wn = w >> 1;
  const int lm = lane & 15, quad = lane >> 4;
  const int m0 = blockIdx.y * 128, n0 = blockIdx.x * 128;
  const __bf16* A = Wc_t + blockIdx.z * 512;
  __bf16* out = Wp_bt + blockIdx.z * 512;
  f32x4 acc[4][4] = {};
  for (int k0 = 0; k0 < 512; k0 += 64) {
#pragma unroll
    for (int it = 0; it < 4; ++it) {
      const int c = w * 4 + it;
      const int e = c * 512 + lane * 8;
      const int row = e >> 6, col = e & 63;
      gld_lds16(A + (size_t)(m0 + row) * 2048 + k0 + col, &As[c * 512]);
      gld_lds16(Wob + (size_t)(n0 + row) * 512 + k0 + col, &Bs[c * 512]);
    }
    __syncthreads();
#pragma unroll
    for (int ks = 0; ks < 2; ++ks) {
      bf16x8 af[4], bfr[4];
#pragma unroll
      for (int i = 0; i < 4; ++i)
        af[i] = *(const bf16x8*)&As[(wm * 64 + i * 16 + lm) * 64 + ks * 32 + quad * 8];
#pragma unroll
      for (int j = 0; j < 4; ++j)
        bfr[j] = *(const bf16x8*)&Bs[(wn * 64 + j * 16 + lm) * 64 + ks * 32 + quad * 8];
#pragma unroll
      for (int i = 0; i < 4; ++i)
#pragma unroll
        for (int j = 0; j < 4; ++j)
          acc[i][j] = __builtin_amdgcn_mfma_f32_16x16x32_bf16(af[i], bfr[j], acc[i][j], 0, 0, 0);
    }
    __syncthreads();
  }
#pragma unroll
  for (int j = 0; j < 4; ++j) {
    const int col = n0 + wn * 64 + j * 16 + lm;
#pragma unroll
    for (int i = 0; i < 4; ++i) {
      const int row0 = m0 + wm * 64 + i * 16 + quad * 4;
#pragma unroll
      for (int r = 0; r < 4; ++r)
        out[(size_t)(row0 + r) * 2048 + col] = (__bf16)(acc[i][j][r]);
    }
  }
}

// ---------------------------------------------------------------------------
// Conv (Wo folded): K=2048 GEMM on cat with row gather. BK=64 (round-3 known
// good; BK=128 doubled LDS bank conflicts and regressed). Epilogue: per-tap
// bias suffix computed on the fly from bj[4][512], relu, +x, leaky_relu.
// ---------------------------------------------------------------------------
__global__ __launch_bounds__(256, 2) void conv_gemm_kernel(
    const __bf16* __restrict__ A,   // catb [16384][512]
    const __bf16* __restrict__ Bt,  // Wp_bt [512][2048]
    const float* __restrict__ bc, const float* __restrict__ bj,  // bj[4][512]
    const float* __restrict__ x, float* __restrict__ out,
    const __bf16* __restrict__ zeros) {
  __shared__ __align__(16) __bf16 As[128 * 64];
  __shared__ __align__(16) __bf16 Bs[128 * 64];
  const int tid = threadIdx.x;
  const int w = tid >> 6, lane = tid & 63;
  const int wm = w & 1, wn = w >> 1;
  const int lm = lane & 15, quad = lane >> 4;
  int m0, n0;
  swizzle_mn(&m0, &n0);
  f32x4 acc[4][4] = {};
  for (int k0 = 0; k0 < 4 * Cch; k0 += 64) {
    const int jtap = k0 >> 9;
    const int shift = 4 * jtap - 12;
    const int cin0 = k0 & 511;
#pragma unroll
    for (int it = 0; it < 4; ++it) {
      const int c = w * 4 + it;
      const int e = c * 512 + lane * 8;
      const int row = e >> 6, col = e & 63;
      const int m = m0 + row;
      const __bf16* src = (((m & (Tseq - 1)) + shift) >= 0)
                              ? A + (size_t)(m + shift) * Cch + cin0 + col
                              : zeros + (lane & 7) * 8;
      gld_lds16(src, &As[c * 512]);
      gld_lds16(Bt + (size_t)(n0 + row) * 2048 + k0 + col, &Bs[c * 512]);
    }
    __syncthreads();
#pragma unroll
    for (int ks = 0; ks < 2; ++ks) {
      bf16x8 af[4], bfr[4];
#pragma unroll
      for (int i = 0; i < 4; ++i)
        af[i] = *(const bf16x8*)&As[(wm * 64 + i * 16 + lm) * 64 + ks * 32 + quad * 8];
#pragma unroll
      for (int j = 0; j < 4; ++j)
        bfr[j] = *(const bf16x8*)&Bs[(wn * 64 + j * 16 + lm) * 64 + ks * 32 + quad * 8];
#pragma unroll
      for (int i = 0; i < 4; ++i)
#pragma unroll
        for (int j = 0; j < 4; ++j)
          acc[i][j] = __builtin_amdgcn_mfma_f32_16x16x32_bf16(af[i], bfr[j], acc[i][j], 0, 0, 0);
    }
    __syncthreads();
  }
#pragma unroll
  for (int j = 0; j < 4; ++j) {
    const int col = n0 + wn * 64 + j * 16 + lm;
    const float bcv = bc[col];
    // suffix sums of per-tap bias: suf[jm] = sum_{j'>=jm} bj[j'][col]
    float suf[4];
    suf[3] = bj[3 * 512 + col];
    suf[2] = suf[3] + bj[2 * 512 + col];
    suf[1] = suf[2] + bj[1 * 512 + col];
    suf[0] = suf[1] + bj[0 * 512 + col];
#pragma unroll
    for (int i = 0; i < 4; ++i) {
      const int row0 = m0 + wm * 64 + i * 16 + quad * 4;
#pragma unroll
      for (int r = 0; r < 4; ++r) {
        const int row = row0 + r;
        const int tl = row & (Tseq - 1);
        int jm = 15 - tl;
        jm = (jm < 0) ? 0 : (jm >> 2);
        float v = acc[i][j][r] + bcv + suf[jm];
        v = fmaxf(v, 0.f);
        v += x[(size_t)row * Cch + col];
        out[(size_t)row * Cch + col] = (v >= 0.f) ? v : 0.2f * v;
      }
    }
  }
}

// ---------------------------------------------------------------------------
// Banded attention: 16-lane groups, bf16x8 loads. grid (T/16, B*H), 256 thr.
// ---------------------------------------------------------------------------
__global__ __launch_bounds__(256) void attn_band_kernel(
    const __bf16* __restrict__ qkv, __bf16* __restrict__ cat) {
  const int tid = threadIdx.x;
  const int tsub = tid >> 4, g = tid & 15;
  const int t = blockIdx.x * 16 + tsub;
  const int bh = blockIdx.y;
  const int b = bh >> 2, h = bh & 3;
  const int d0 = g * 8;
  const size_t base = ((size_t)(b * Tseq + t)) * Nqkv + h * 128 + d0;
  bf16x8 qv = *(const bf16x8*)(qkv + base);
  const float scale = 0.08838834764831845f;  // 1/sqrt(128)
  float score[7];
#pragma unroll
  for (int i = 0; i < 7; ++i) {
    const int s = t - 3 + i;
    const bool valid = (s >= 0) && (s < Tseq);
    float p = 0.f;
    if (valid) {
      bf16x8 kv = *(const bf16x8*)(qkv + base + (size_t)(i - 3) * Nqkv + 512);
#pragma unroll
      for (int e = 0; e < 8; ++e) p += (float)qv[e] * (float)kv[e];
    }
    p += __shfl_xor(p, 1);
    p += __shfl_xor(p, 2);
    p += __shfl_xor(p, 4);
    p += __shfl_xor(p, 8);
    score[i] = valid ? p * scale : -1e30f;
  }
  float mx = score[0];
#pragma unroll
  for (int i = 1; i < 7; ++i) mx = fmaxf(mx, score[i]);
  float wgt[7], denom = 0.f;
#pragma unroll
  for (int i = 0; i < 7; ++i) {
    wgt[i] = (score[i] > -1e29f) ? expf(score[i] - mx) : 0.f;
    denom += wgt[i];
  }
  const float inv = 1.f / denom;
  float o[8] = {};
#pragma unroll
  for (int i = 0; i < 7; ++i) {
    if (wgt[i] != 0.f) {
      bf16x8 vv = *(const bf16x8*)(qkv + base + (size_t)(i - 3) * Nqkv + 1024);
#pragma unroll
      for (int e = 0; e < 8; ++e) o[e] += wgt[i] * (float)vv[e];
    }
  }
  bf16x8 ov;
#pragma unroll
  for (int e = 0; e < 8; ++e) ov[e] = (__bf16)(o[e] * inv);
  *(bf16x8*)(cat + ((size_t)(b * Tseq + t)) * Cch + h * 128 + d0) = ov;
}

// ---------------------------------------------------------------------------
// ONE prep kernel (flat grid), replaces 6 small launches:
//  [0,8192)       cast x -> xb (bf16)
//  [8192,8960)    transpose-cast Wq/Wk/Wv -> Wqkv_t [1536][512]
//  [8960,9984)    transpose-cast Wc (2048x512) -> Wc_t [512][2048]
//  [9984,10240)   cast Wo -> Wob (row-major)
//  10240          zero-fill zeros buffer
//  [10241,10273)  bias partials bj[j][n] = sum_ci bo[ci]*Wc[j,ci,n]
// ---------------------------------------------------------------------------
#define PREP_A 8192
#define PREP_B 8960
#define PREP_C 9984
#define PREP_D 10240
#define PREP_E 10241
#define PREP_N 10273

__global__ __launch_bounds__(256) void prep_kernel(
    const float* __restrict__ x, const float* __restrict__ Wq,
    const float* __restrict__ Wk, const float* __restrict__ Wv,
    const float* __restrict__ Wo, const float* __restrict__ Wc,
    const float* __restrict__ bo,
    __bf16* __restrict__ xb, __bf16* __restrict__ Wqkv_t,
    __bf16* __restrict__ Wc_t, __bf16* __restrict__ Wob,
    float* __restrict__ bj, __bf16* __restrict__ zeros) {
  __shared__ float sArr[32][33];
  __shared__ float red[256];
  const int bid = blockIdx.x;
  const int tid = threadIdx.x;
  if (bid < PREP_A) {
    // cast x
    const size_t i = ((size_t)bid * 256 + tid) * 4;
    float4 v = *(const float4*)(x + i);
    bf16x4 o;
    o[0] = (__bf16)v.x; o[1] = (__bf16)v.y; o[2] = (__bf16)v.z; o[3] = (__bf16)v.w;
    *(bf16x4*)(xb + i) = o;
  } else if (bid < PREP_B) {
    // transpose Wqkv: local = (bx:4, by:16, z:12); src[512][128] -> dst[128][512]
    const int l = bid - PREP_A;
    const int bx = l & 3, by = (l >> 2) & 15, z = l >> 6;
    const int sgrp = z >> 2, h = z & 3;
    const float* src = ((sgrp == 0) ? Wq : (sgrp == 1) ? Wk : Wv) + h * (512 * 128);
    __bf16* dst = Wqkv_t + (size_t)z * 128 * 512;
    const int tx = tid & 31, ty = tid >> 5;
    const int c0 = bx * 32, r0 = by * 32;
#pragma unroll
    for (int rr = 0; rr < 4; ++rr)
      sArr[ty + rr * 8][tx] = src[(size_t)(r0 + ty + rr * 8) * 128 + c0 + tx];
    __syncthreads();
#pragma unroll
    for (int rr = 0; rr < 4; ++rr)
      dst[(size_t)(c0 + ty + rr * 8) * 512 + r0 + tx] = (__bf16)sArr[tx][ty + rr * 8];
  } else if (bid < PREP_C) {
    // transpose Wc: local = (bx:16, by:64); src[2048][512] -> dst[512][2048]
    const int l = bid - PREP_B;
    const int bx = l & 15, by = l >> 4;
    const int tx = tid & 31, ty = tid >> 5;
    const int c0 = bx * 32, r0 = by * 32;
#pragma unroll
    for (int rr = 0; rr < 4; ++rr)
      sArr[ty + rr * 8][tx] = Wc[(size_t)(r0 + ty + rr * 8) * 512 + c0 + tx];
    __syncthreads();
#pragma unroll
    for (int rr = 0; rr < 4; ++rr)
      Wc_t[(size_t)(c0 + ty + rr * 8) * 2048 + r0 + tx] = (__bf16)sArr[tx][ty + rr * 8];
  } else if (bid < PREP_D) {
    // cast Wo
    const int l = bid - PREP_C;
    const size_t i = ((size_t)l * 256 + tid) * 4;
    float4 v = *(const float4*)(Wo + i);
    bf16x4 o;
    o[0] = (__bf16)v.x; o[1] = (__bf16)v.y; o[2] = (__bf16)v.z; o[3] = (__bf16)v.w;
    *(bf16x4*)(Wob + i) = o;
  } else if (bid < PREP_E) {
    bf16x8 zero = {};
    *(bf16x8*)(zeros + tid * 8) = zero;
  } else {
    // bias partials: l = (j:4, nb:8); n = nb*64 + (tid&63), cig = tid>>6
    const int l = bid - PREP_E;
    const int j = l >> 3, nb = l & 7;
    const int n = nb * 64 + (tid & 63);
    const int cig = tid >> 6;
    const float* base = Wc + ((size_t)j * 512 + cig * 128) * 512 + n;
    float acc = 0.f;
#pragma unroll 8
    for (int ci = 0; ci < 128; ++ci) acc += bo[cig * 128 + ci] * base[(size_t)ci * 512];
    red[tid] = acc;
    __syncthreads();
    if (tid < 64)
      bj[j * 512 + n] = red[tid] + red[tid + 64] + red[tid + 128] + red[tid + 192];
  }
}

// ---------------------------------------------------------------------------
extern "C" void kernel_launch(void* const* d_in, const int* in_sizes, int n_in,
                              void* d_out, int out_size, void* d_ws, size_t ws_size,
                              hipStream_t stream) {
  const float* x  = (const float*)d_in[0];
  const float* Wq = (const float*)d_in[1];
  const float* bq = (const float*)d_in[2];
  const float* Wk = (const float*)d_in[3];
  const float* bk = (const float*)d_in[4];
  const float* Wv = (const float*)d_in[5];
  const float* bv = (const float*)d_in[6];
  const float* Wo = (const float*)d_in[7];
  const float* bo = (const float*)d_in[8];
  const float* Wc = (const float*)d_in[9];
  const float* bc = (const float*)d_in[10];
  float* out = (float*)d_out;

  char* p = (char*)d_ws;
  __bf16* xb     = (__bf16*)p;  p += (size_t)Mrows * Cch * 2;    // 16 MiB
  __bf16* qkv    = (__bf16*)p;  p += (size_t)Mrows * Nqkv * 2;   // 48 MiB
  __bf16* catb   = (__bf16*)p;  p += (size_t)Mrows * Cch * 2;    // 16 MiB
  __bf16* Wqkv_t = (__bf16*)p;  p += (size_t)Nqkv * Cch * 2;     // 1.5 MiB
  __bf16* Wc_t   = (__bf16*)p;  p += (size_t)Cch * 2048 * 2;     // 2 MiB
  __bf16* Wob    = (__bf16*)p;  p += (size_t)Cch * Cch * 2;      // 0.5 MiB
  __bf16* Wp_bt  = (__bf16*)p;  p += (size_t)Cch * 2048 * 2;     // 2 MiB
  float*  bj     = (float*)p;   p += 4 * Cch * 4;                // 8 KiB
  __bf16* zeros  = (__bf16*)p;  p += 4096;

  prep_kernel<<<PREP_N, 256, 0, stream>>>(x, Wq, Wk, Wv, Wo, Wc, bo,
                                          xb, Wqkv_t, Wc_t, Wob, bj, zeros);

  // Wp[j] = Wo @ Wc[j]  (folds the head-combine GEMM into the conv weights)
  gemm_wp_kernel<<<dim3(4, 4, 4), 256, 0, stream>>>(Wc_t, Wob, Wp_bt);

  gemm_bt_bf16_kernel<<<dim3(Nqkv / 128, Mrows / 128), 256, 0, stream>>>(
      xb, Cch, Wqkv_t, Cch, bq, bk, bv, qkv, Nqkv);

  attn_band_kernel<<<dim3(Tseq / 16, Bb * 4), 256, 0, stream>>>(qkv, catb);

  conv_gemm_kernel<<<dim3(Cch / 128, Mrows / 128), 256, 0, stream>>>(
      catb, Wp_bt, bc, bj, x, out, zeros);
}

// Round 6
// 214.578 us; speedup vs baseline: 5.1279x; 1.0845x over previous
//
#include <hip/hip_runtime.h>
#include <math.h>

#define Bb    8
#define Tseq  2048
#define Cch   512
#define Mrows 16384
#define Nqkv  1536

typedef __bf16 bf16x8 __attribute__((ext_vector_type(8)));
typedef __bf16 bf16x4 __attribute__((ext_vector_type(4)));
typedef float  f32x4  __attribute__((ext_vector_type(4)));

__device__ __forceinline__ void gld_lds16(const void* g, void* l) {
  __builtin_amdgcn_global_load_lds(
      (const __attribute__((address_space(1))) unsigned int*)g,
      (__attribute__((address_space(3))) unsigned int*)l, 16, 0, 0);
}

// LDS bank-conflict-killing XOR swizzle: row r's 8-element group g lives at
// group (g ^ (r&7)). Read offset for (row, group): SWZ(r,g). After swizzle a
// fragment read loads every bank exactly 8 words/wave = the b128 minimum
// (unswizzled: 16 lanes/quad alias one 4-bank group -> 2x LDS time, the
// 1.26e7 SQ_LDS_BANK_CONFLICT seen in rounds 2-5).
#define SWZ(r, g) (((r) << 6) + ((((g) ^ ((r) & 7))) << 3))

// XCD-aware remap: blocks with the same m-tile group land on one XCD's L2.
__device__ __forceinline__ void swizzle_mn(int* m0, int* n0) {
  const int NX = gridDim.x;
  const int total = NX * gridDim.y;
  const int lid = blockIdx.y * NX + blockIdx.x;
  const int xcd = lid & 7;
  const int chunk = lid >> 3;
  const int idx = xcd * (total >> 3) + chunk;
  const int mt = idx / NX;
  const int nt = idx - mt * NX;
  *m0 = mt * 128;
  *n0 = nt * 128;
}

// ---------------------------------------------------------------------------
// Fused QKV-projection + Wp-precompute GEMM (both depend only on prep, both
// K=512). Blocks [0,1536): qkv = xb @ Wqkv_t^T + bias -> [16384][1536].
// Blocks [1536,1600): Wp[z] = Wc[z]^T-major @ Wo^T -> Wp_bt [512][2048].
// Tile 128x128, BK=64, 4 waves (2x2), wave 64x64 via 4x4 MFMA 16x16x32.
// ---------------------------------------------------------------------------
__global__ __launch_bounds__(256, 2) void gemm_qkv_wp_kernel(
    const __bf16* __restrict__ xb, const __bf16* __restrict__ Wqkv_t,
    const float* __restrict__ bq, const float* __restrict__ bk,
    const float* __restrict__ bv, __bf16* __restrict__ qkv,
    const __bf16* __restrict__ Wc_t, const __bf16* __restrict__ Wob,
    __bf16* __restrict__ Wp_bt) {
  __shared__ __align__(16) __bf16 As[128 * 64];
  __shared__ __align__(16) __bf16 Bs[128 * 64];
  const int tid = threadIdx.x;
  const int w = tid >> 6, lane = tid & 63;
  const int wm = w & 1, wn = w >> 1;
  const int lm = lane & 15, quad = lane >> 4;
  const int srow = lane >> 3;                 // staging row-in-chunk
  const int scol = (((lane & 7) ^ srow) << 3);  // staging swizzled col
  const int lid = blockIdx.x;

  const __bf16 *Ap, *Bp;
  __bf16* op;
  int lda, ldo, m0, n0;
  bool dobias;
  if (lid < 1536) {
    const int xcd = lid & 7, chunk = lid >> 3;
    const int idx = xcd * 192 + chunk;
    const int mt = idx / 12, nt = idx - mt * 12;
    m0 = mt * 128; n0 = nt * 128;
    Ap = xb; lda = 512; Bp = Wqkv_t;
    op = qkv; ldo = 1536; dobias = true;
  } else {
    const int l2 = lid - 1536;
    const int z = l2 >> 4;
    m0 = ((l2 >> 2) & 3) * 128; n0 = (l2 & 3) * 128;
    Ap = Wc_t + z * 512; lda = 2048; Bp = Wob;
    op = Wp_bt + z * 512; ldo = 2048; dobias = false;
  }

  f32x4 acc[4][4] = {};
  for (int k0 = 0; k0 < 512; k0 += 64) {
#pragma unroll
    for (int it = 0; it < 4; ++it) {
      const int c = w * 4 + it;
      const int row = c * 8 + srow;
      gld_lds16(Ap + (size_t)(m0 + row) * lda + k0 + scol, &As[c * 512]);
      gld_lds16(Bp + (size_t)(n0 + row) * 512 + k0 + scol, &Bs[c * 512]);
    }
    __syncthreads();
#pragma unroll
    for (int ks = 0; ks < 2; ++ks) {
      bf16x8 af[4], bfr[4];
#pragma unroll
      for (int i = 0; i < 4; ++i)
        af[i] = *(const bf16x8*)&As[SWZ(wm * 64 + i * 16 + lm, ks * 4 + quad)];
#pragma unroll
      for (int j = 0; j < 4; ++j)
        bfr[j] = *(const bf16x8*)&Bs[SWZ(wn * 64 + j * 16 + lm, ks * 4 + quad)];
#pragma unroll
      for (int i = 0; i < 4; ++i)
#pragma unroll
        for (int j = 0; j < 4; ++j)
          acc[i][j] = __builtin_amdgcn_mfma_f32_16x16x32_bf16(af[i], bfr[j], acc[i][j], 0, 0, 0);
    }
    __syncthreads();
  }
#pragma unroll
  for (int j = 0; j < 4; ++j) {
    const int col = n0 + wn * 64 + j * 16 + lm;
    float bias = 0.f;
    if (dobias) {
      const int s = col >> 9;
      const float* bp = (s == 0) ? bq : (s == 1 ? bk : bv);
      bias = bp[col & 511];
    }
#pragma unroll
    for (int i = 0; i < 4; ++i) {
      const int row0 = m0 + wm * 64 + i * 16 + quad * 4;
#pragma unroll
      for (int r = 0; r < 4; ++r)
        op[(size_t)(row0 + r) * ldo + col] = (__bf16)(acc[i][j][r] + bias);
    }
  }
}

// ---------------------------------------------------------------------------
// Conv (Wo folded): K=2048 GEMM on cat with row gather, BK=64, swizzled LDS.
// Epilogue: per-tap bias suffix from bj[4][512], relu, +x (fp32), leaky_relu.
// ---------------------------------------------------------------------------
__global__ __launch_bounds__(256, 2) void conv_gemm_kernel(
    const __bf16* __restrict__ A,   // catb [16384][512]
    const __bf16* __restrict__ Bt,  // Wp_bt [512][2048]
    const float* __restrict__ bc, const float* __restrict__ bj,  // bj[4][512]
    const float* __restrict__ x, float* __restrict__ out,
    const __bf16* __restrict__ zeros) {
  __shared__ __align__(16) __bf16 As[128 * 64];
  __shared__ __align__(16) __bf16 Bs[128 * 64];
  const int tid = threadIdx.x;
  const int w = tid >> 6, lane = tid & 63;
  const int wm = w & 1, wn = w >> 1;
  const int lm = lane & 15, quad = lane >> 4;
  const int srow = lane >> 3;
  const int scol = (((lane & 7) ^ srow) << 3);
  int m0, n0;
  swizzle_mn(&m0, &n0);
  f32x4 acc[4][4] = {};
  for (int k0 = 0; k0 < 4 * Cch; k0 += 64) {
    const int jtap = k0 >> 9;
    const int shift = 4 * jtap - 12;
    const int cin0 = k0 & 511;
#pragma unroll
    for (int it = 0; it < 4; ++it) {
      const int c = w * 4 + it;
      const int row = c * 8 + srow;
      const int m = m0 + row;
      const __bf16* src = (((m & (Tseq - 1)) + shift) >= 0)
                              ? A + (size_t)(m + shift) * Cch + cin0 + scol
                              : zeros + scol;
      gld_lds16(src, &As[c * 512]);
      gld_lds16(Bt + (size_t)(n0 + row) * 2048 + k0 + scol, &Bs[c * 512]);
    }
    __syncthreads();
#pragma unroll
    for (int ks = 0; ks < 2; ++ks) {
      bf16x8 af[4], bfr[4];
#pragma unroll
      for (int i = 0; i < 4; ++i)
        af[i] = *(const bf16x8*)&As[SWZ(wm * 64 + i * 16 + lm, ks * 4 + quad)];
#pragma unroll
      for (int j = 0; j < 4; ++j)
        bfr[j] = *(const bf16x8*)&Bs[SWZ(wn * 64 + j * 16 + lm, ks * 4 + quad)];
#pragma unroll
      for (int i = 0; i < 4; ++i)
#pragma unroll
        for (int j = 0; j < 4; ++j)
          acc[i][j] = __builtin_amdgcn_mfma_f32_16x16x32_bf16(af[i], bfr[j], acc[i][j], 0, 0, 0);
    }
    __syncthreads();
  }
#pragma unroll
  for (int j = 0; j < 4; ++j) {
    const int col = n0 + wn * 64 + j * 16 + lm;
    const float bcv = bc[col];
    float suf[4];
    suf[3] = bj[3 * 512 + col];
    suf[2] = suf[3] + bj[2 * 512 + col];
    suf[1] = suf[2] + bj[1 * 512 + col];
    suf[0] = suf[1] + bj[0 * 512 + col];
#pragma unroll
    for (int i = 0; i < 4; ++i) {
      const int row0 = m0 + wm * 64 + i * 16 + quad * 4;
#pragma unroll
      for (int r = 0; r < 4; ++r) {
        const int row = row0 + r;
        const int tl = row & (Tseq - 1);
        int jm = 15 - tl;
        jm = (jm < 0) ? 0 : (jm >> 2);
        float v = acc[i][j][r] + bcv + suf[jm];
        v = fmaxf(v, 0.f);
        v += x[(size_t)row * Cch + col];
        out[(size_t)row * Cch + col] = (v >= 0.f) ? v : 0.2f * v;
      }
    }
  }
}

// ---------------------------------------------------------------------------
// Banded attention: 16-lane groups, bf16x8 loads. grid (T/16, B*H), 256 thr.
// ---------------------------------------------------------------------------
__global__ __launch_bounds__(256) void attn_band_kernel(
    const __bf16* __restrict__ qkv, __bf16* __restrict__ cat) {
  const int tid = threadIdx.x;
  const int tsub = tid >> 4, g = tid & 15;
  const int t = blockIdx.x * 16 + tsub;
  const int bh = blockIdx.y;
  const int b = bh >> 2, h = bh & 3;
  const int d0 = g * 8;
  const size_t base = ((size_t)(b * Tseq + t)) * Nqkv + h * 128 + d0;
  bf16x8 qv = *(const bf16x8*)(qkv + base);
  const float scale = 0.08838834764831845f;  // 1/sqrt(128)
  float score[7];
#pragma unroll
  for (int i = 0; i < 7; ++i) {
    const int s = t - 3 + i;
    const bool valid = (s >= 0) && (s < Tseq);
    float p = 0.f;
    if (valid) {
      bf16x8 kv = *(const bf16x8*)(qkv + base + (size_t)(i - 3) * Nqkv + 512);
#pragma unroll
      for (int e = 0; e < 8; ++e) p += (float)qv[e] * (float)kv[e];
    }
    p += __shfl_xor(p, 1);
    p += __shfl_xor(p, 2);
    p += __shfl_xor(p, 4);
    p += __shfl_xor(p, 8);
    score[i] = valid ? p * scale : -1e30f;
  }
  float mx = score[0];
#pragma unroll
  for (int i = 1; i < 7; ++i) mx = fmaxf(mx, score[i]);
  float wgt[7], denom = 0.f;
#pragma unroll
  for (int i = 0; i < 7; ++i) {
    wgt[i] = (score[i] > -1e29f) ? expf(score[i] - mx) : 0.f;
    denom += wgt[i];
  }
  const float inv = 1.f / denom;
  float o[8] = {};
#pragma unroll
  for (int i = 0; i < 7; ++i) {
    if (wgt[i] != 0.f) {
      bf16x8 vv = *(const bf16x8*)(qkv + base + (size_t)(i - 3) * Nqkv + 1024);
#pragma unroll
      for (int e = 0; e < 8; ++e) o[e] += wgt[i] * (float)vv[e];
    }
  }
  bf16x8 ov;
#pragma unroll
  for (int e = 0; e < 8; ++e) ov[e] = (__bf16)(o[e] * inv);
  *(bf16x8*)(cat + ((size_t)(b * Tseq + t)) * Cch + h * 128 + d0) = ov;
}

// ---------------------------------------------------------------------------
// ONE prep kernel (flat grid):
//  [0,8192)       cast x -> xb (bf16)
//  [8192,8960)    transpose-cast Wq/Wk/Wv -> Wqkv_t [1536][512]
//  [8960,9984)    transpose-cast Wc (2048x512) -> Wc_t [512][2048]
//  [9984,10240)   cast Wo -> Wob (row-major)
//  10240          zero-fill zeros buffer
//  [10241,10273)  bias partials bj[j][n] = sum_ci bo[ci]*Wc[j,ci,n]
// ---------------------------------------------------------------------------
#define PREP_A 8192
#define PREP_B 8960
#define PREP_C 9984
#define PREP_D 10240
#define PREP_E 10241
#define PREP_N 10273

__global__ __launch_bounds__(256) void prep_kernel(
    const float* __restrict__ x, const float* __restrict__ Wq,
    const float* __restrict__ Wk, const float* __restrict__ Wv,
    const float* __restrict__ Wo, const float* __restrict__ Wc,
    const float* __restrict__ bo,
    __bf16* __restrict__ xb, __bf16* __restrict__ Wqkv_t,
    __bf16* __restrict__ Wc_t, __bf16* __restrict__ Wob,
    float* __restrict__ bj, __bf16* __restrict__ zeros) {
  __shared__ float sArr[32][33];
  __shared__ float red[256];
  const int bid = blockIdx.x;
  const int tid = threadIdx.x;
  if (bid < PREP_A) {
    const size_t i = ((size_t)bid * 256 + tid) * 4;
    float4 v = *(const float4*)(x + i);
    bf16x4 o;
    o[0] = (__bf16)v.x; o[1] = (__bf16)v.y; o[2] = (__bf16)v.z; o[3] = (__bf16)v.w;
    *(bf16x4*)(xb + i) = o;
  } else if (bid < PREP_B) {
    const int l = bid - PREP_A;
    const int bx = l & 3, by = (l >> 2) & 15, z = l >> 6;
    const int sgrp = z >> 2, h = z & 3;
    const float* src = ((sgrp == 0) ? Wq : (sgrp == 1) ? Wk : Wv) + h * (512 * 128);
    __bf16* dst = Wqkv_t + (size_t)z * 128 * 512;
    const int tx = tid & 31, ty = tid >> 5;
    const int c0 = bx * 32, r0 = by * 32;
#pragma unroll
    for (int rr = 0; rr < 4; ++rr)
      sArr[ty + rr * 8][tx] = src[(size_t)(r0 + ty + rr * 8) * 128 + c0 + tx];
    __syncthreads();
#pragma unroll
    for (int rr = 0; rr < 4; ++rr)
      dst[(size_t)(c0 + ty + rr * 8) * 512 + r0 + tx] = (__bf16)sArr[tx][ty + rr * 8];
  } else if (bid < PREP_C) {
    const int l = bid - PREP_B;
    const int bx = l & 15, by = l >> 4;
    const int tx = tid & 31, ty = tid >> 5;
    const int c0 = bx * 32, r0 = by * 32;
#pragma unroll
    for (int rr = 0; rr < 4; ++rr)
      sArr[ty + rr * 8][tx] = Wc[(size_t)(r0 + ty + rr * 8) * 512 + c0 + tx];
    __syncthreads();
#pragma unroll
    for (int rr = 0; rr < 4; ++rr)
      Wc_t[(size_t)(c0 + ty + rr * 8) * 2048 + r0 + tx] = (__bf16)sArr[tx][ty + rr * 8];
  } else if (bid < PREP_D) {
    const int l = bid - PREP_C;
    const size_t i = ((size_t)l * 256 + tid) * 4;
    float4 v = *(const float4*)(Wo + i);
    bf16x4 o;
    o[0] = (__bf16)v.x; o[1] = (__bf16)v.y; o[2] = (__bf16)v.z; o[3] = (__bf16)v.w;
    *(bf16x4*)(Wob + i) = o;
  } else if (bid < PREP_E) {
    bf16x8 zero = {};
    *(bf16x8*)(zeros + tid * 8) = zero;
  } else {
    const int l = bid - PREP_E;
    const int j = l >> 3, nb = l & 7;
    const int n = nb * 64 + (tid & 63);
    const int cig = tid >> 6;
    const float* base = Wc + ((size_t)j * 512 + cig * 128) * 512 + n;
    float acc = 0.f;
#pragma unroll 8
    for (int ci = 0; ci < 128; ++ci) acc += bo[cig * 128 + ci] * base[(size_t)ci * 512];
    red[tid] = acc;
    __syncthreads();
    if (tid < 64)
      bj[j * 512 + n] = red[tid] + red[tid + 64] + red[tid + 128] + red[tid + 192];
  }
}

// ---------------------------------------------------------------------------
extern "C" void kernel_launch(void* const* d_in, const int* in_sizes, int n_in,
                              void* d_out, int out_size, void* d_ws, size_t ws_size,
                              hipStream_t stream) {
  const float* x  = (const float*)d_in[0];
  const float* Wq = (const float*)d_in[1];
  const float* bq = (const float*)d_in[2];
  const float* Wk = (const float*)d_in[3];
  const float* bk = (const float*)d_in[4];
  const float* Wv = (const float*)d_in[5];
  const float* bv = (const float*)d_in[6];
  const float* Wo = (const float*)d_in[7];
  const float* bo = (const float*)d_in[8];
  const float* Wc = (const float*)d_in[9];
  const float* bc = (const float*)d_in[10];
  float* out = (float*)d_out;

  char* p = (char*)d_ws;
  __bf16* xb     = (__bf16*)p;  p += (size_t)Mrows * Cch * 2;    // 16 MiB
  __bf16* qkv    = (__bf16*)p;  p += (size_t)Mrows * Nqkv * 2;   // 48 MiB
  __bf16* catb   = (__bf16*)p;  p += (size_t)Mrows * Cch * 2;    // 16 MiB
  __bf16* Wqkv_t = (__bf16*)p;  p += (size_t)Nqkv * Cch * 2;     // 1.5 MiB
  __bf16* Wc_t   = (__bf16*)p;  p += (size_t)Cch * 2048 * 2;     // 2 MiB
  __bf16* Wob    = (__bf16*)p;  p += (size_t)Cch * Cch * 2;      // 0.5 MiB
  __bf16* Wp_bt  = (__bf16*)p;  p += (size_t)Cch * 2048 * 2;     // 2 MiB
  float*  bj     = (float*)p;   p += 4 * Cch * 4;                // 8 KiB
  __bf16* zeros  = (__bf16*)p;  p += 4096;

  prep_kernel<<<PREP_N, 256, 0, stream>>>(x, Wq, Wk, Wv, Wo, Wc, bo,
                                          xb, Wqkv_t, Wc_t, Wob, bj, zeros);

  // QKV projection + Wp = Wo @ Wc[j] precompute, fused into one launch
  gemm_qkv_wp_kernel<<<1600, 256, 0, stream>>>(xb, Wqkv_t, bq, bk, bv, qkv,
                                               Wc_t, Wob, Wp_bt);

  attn_band_kernel<<<dim3(Tseq / 16, Bb * 4), 256, 0, stream>>>(qkv, catb);

  conv_gemm_kernel<<<dim3(Cch / 128, Mrows / 128), 256, 0, stream>>>(
      catb, Wp_bt, bc, bj, x, out, zeros);
}